// Round 6
// baseline (437.873 us; speedup 1.0000x reference)
//
#include <hip/hip_runtime.h>
#include <hip/hip_bf16.h>
#include <stdint.h>

// ---------------------------------------------------------------------------
// CrossViewIPAttnProcessor on MI355X (gfx950)
// B=8, Lq=4096, D=1024, Dc=768, H=16, HD=64, text=77 keys, ip=4 keys
// Round 6: GEMMs -> m97 geometry: 128x128 tile, BK=32, 4 waves, 32KB LDS,
// 4 blocks/CU, 1 barrier + vmcnt(0) per K-tile (cross-block TLP covers the
// drain), T2 swizzle, T5 setprio. qgemm: inline fp32->bf16 A (cvt_hs removed),
// LDS-routed bf16 epilogue (kills 2x write amplification).
// ---------------------------------------------------------------------------

typedef __attribute__((ext_vector_type(8))) short short8;
typedef __attribute__((ext_vector_type(4))) float f32x4;
typedef __attribute__((ext_vector_type(8))) float float8_t;
typedef __attribute__((ext_vector_type(8))) __bf16 bf16x8;
typedef __attribute__((ext_vector_type(4))) __bf16 bf16x4;

__device__ __forceinline__ ushort f2b(float f) {
  __bf16 h = (__bf16)f;
  return __builtin_bit_cast(ushort, h);
}

__device__ __forceinline__ short8 pack2(float4 a, float4 b) {
  float8_t v;
  v[0] = a.x; v[1] = a.y; v[2] = a.z; v[3] = a.w;
  v[4] = b.x; v[5] = b.y; v[6] = b.z; v[7] = b.w;
  return __builtin_bit_cast(short8, __builtin_convertvector(v, bf16x8));
}

#define GLD16(gp, lp) \
  __builtin_amdgcn_global_load_lds((const __attribute__((address_space(1))) uint32_t*)(gp), \
                                   (__attribute__((address_space(3))) uint32_t*)(lp), 16, 0, 0)

#define FENCE_SCHED() __builtin_amdgcn_sched_barrier(0)

// --------------------- 1) fused fp32 -> bf16 for 6 weights ------------------
struct CvtArgs {
  const float* src[6];
  ushort* dst[6];
  int n4[6];
};

__global__ __launch_bounds__(256) void k_cvt_all(CvtArgs a) {
  int seg = blockIdx.y;
  int i = blockIdx.x * blockDim.x + threadIdx.x;
  if (i >= a.n4[seg]) return;
  float4 v = reinterpret_cast<const float4*>(a.src[seg])[i];
  bf16x4 h;
  h[0] = (__bf16)v.x; h[1] = (__bf16)v.y; h[2] = (__bf16)v.z; h[3] = (__bf16)v.w;
  reinterpret_cast<ushort4*>(a.dst[seg])[i] = __builtin_bit_cast(ushort4, h);
}

// --------------------------- 2) Xn builder ---------------------------------
__global__ __launch_bounds__(256) void k_build_xn(const float* __restrict__ enc,
                                                  const float* __restrict__ lnw,
                                                  const float* __restrict__ lnb,
                                                  ushort* __restrict__ xn) {
  const int Dc = 768;
  int tok = blockIdx.x, b = blockIdx.y, t = threadIdx.x;
  ushort* out = xn + ((size_t)b * 96 + tok) * Dc;
  bool padrow = (tok >= 84) || (tok >= 77 && tok < 80);
  if (padrow) { out[t] = 0; out[t + 256] = 0; out[t + 512] = 0; return; }
  const float* src = (tok < 77) ? enc + ((size_t)b * 81 + tok) * Dc
                                : enc + ((size_t)b * 81 + 77 + (tok - 80)) * Dc;
  float x0 = src[t], x1 = src[t + 256], x2 = src[t + 512];
  if (tok >= 80) { out[t] = f2b(x0); out[t + 256] = f2b(x1); out[t + 512] = f2b(x2); return; }
  float s = x0 + x1 + x2, q = x0 * x0 + x1 * x1 + x2 * x2;
  for (int m = 32; m; m >>= 1) { s += __shfl_xor(s, m, 64); q += __shfl_xor(q, m, 64); }
  __shared__ float rs[4], rq[4];
  int w = t >> 6;
  if ((t & 63) == 0) { rs[w] = s; rq[w] = q; }
  __syncthreads();
  s = rs[0] + rs[1] + rs[2] + rs[3];
  q = rq[0] + rq[1] + rq[2] + rq[3];
  float mean = s * (1.0f / 768.0f);
  float var = q * (1.0f / 768.0f) - mean * mean;
  float rstd = rsqrtf(var + 1e-5f);
  out[t]       = f2b((x0 - mean) * rstd * lnw[t]       + lnb[t]);
  out[t + 256] = f2b((x1 - mean) * rstd * lnw[t + 256] + lnb[t + 256]);
  out[t + 512] = f2b((x2 - mean) * rstd * lnw[t + 512] + lnb[t + 512]);
}

// --------------------------- 3) K/V projection -----------------------------
__global__ __launch_bounds__(256) void k_kv(const ushort* __restrict__ xn,
                                            const ushort* __restrict__ wb,
                                            const ushort* __restrict__ wipb,
                                            ushort* __restrict__ out, int mode) {
  int n0 = blockIdx.x * 256, b = blockIdx.y;
  int t = threadIdx.x, w = t >> 6, l = t & 63, lo = l & 15, hi = l >> 4;
  __shared__ alignas(16) ushort Xs[96 * 32];
  __shared__ alignas(16) ushort Ws[256 * 32];
  __shared__ alignas(16) ushort Wip[256 * 32];
  f32x4 acc[6][4];
  f32x4 zf = {0.f, 0.f, 0.f, 0.f};
  for (int i = 0; i < 6; i++) for (int j = 0; j < 4; j++) acc[i][j] = zf;
  const ushort* xb = xn + (size_t)b * 96 * 768;
  for (int k0 = 0; k0 < 768; k0 += 32) {
    __syncthreads();
    for (int i = t; i < 96 * 16; i += 256) {
      int row = i >> 4, p = i & 15;
      reinterpret_cast<uint32_t*>(Xs)[i] =
          *reinterpret_cast<const uint32_t*>(xb + row * 768 + k0 + p * 2);
    }
    for (int i = t; i < 256 * 16; i += 256) {
      int row = i >> 4, p = i & 15;
      reinterpret_cast<uint32_t*>(Ws)[i] =
          *reinterpret_cast<const uint32_t*>(wb + (size_t)(n0 + row) * 768 + k0 + p * 2);
      reinterpret_cast<uint32_t*>(Wip)[i] =
          *reinterpret_cast<const uint32_t*>(wipb + (size_t)(n0 + row) * 768 + k0 + p * 2);
    }
    __syncthreads();
    short8 a[6], bb[4], bip[4];
    for (int mi = 0; mi < 6; mi++)
      a[mi] = *reinterpret_cast<const short8*>(Xs + (mi * 16 + lo) * 32 + hi * 8);
    for (int ni = 0; ni < 4; ni++) {
      bb[ni]  = *reinterpret_cast<const short8*>(Ws  + (w * 64 + ni * 16 + lo) * 32 + hi * 8);
      bip[ni] = *reinterpret_cast<const short8*>(Wip + (w * 64 + ni * 16 + lo) * 32 + hi * 8);
    }
    for (int ni = 0; ni < 4; ni++) {
      for (int mi = 0; mi < 5; mi++)
        acc[mi][ni] = __builtin_amdgcn_mfma_f32_16x16x32_bf16(a[mi], bb[ni], acc[mi][ni], 0, 0, 0);
      acc[5][ni] = __builtin_amdgcn_mfma_f32_16x16x32_bf16(a[5], bip[ni], acc[5][ni], 0, 0, 0);
    }
  }
  for (int mi = 0; mi < 6; mi++)
    for (int ni = 0; ni < 4; ni++) {
      int col = n0 + w * 64 + ni * 16 + lo;
      int h = col >> 6, dd = col & 63;
      for (int j = 0; j < 4; j++) {
        int tok = mi * 16 + hi * 4 + j;
        ushort v = f2b(acc[mi][ni][j]);
        if (mode == 0) out[(((size_t)b * 16 + h) * 96 + tok) * 64 + dd] = v;
        else           out[(((size_t)b * 16 + h) * 64 + dd) * 96 + tok] = v;
      }
    }
}

// --------------- 4/6) m97-style 128x128 BK=32 GEMM, 4 blocks/CU ------------
// AMODE 0: A fp32, inline cvt via reg-stage (qgemm). AMODE 1: A bf16 gload_lds.
// BIASED:  fp32 C + bias direct stores (ogemm). else bf16 C via LDS epilogue.
template <int AMODE, bool BIASED>
__global__ __launch_bounds__(256, 4) void k_gemm32(const void* __restrict__ Av,
                                                   const ushort* __restrict__ Bw,
                                                   const float* __restrict__ bias,
                                                   void* __restrict__ Cv) {
  const int K = 1024, NT = 32;
  int wg = blockIdx.x;
  int nid = (wg & 7) * 256 + (wg >> 3);   // XCD-chunked, nwg=2048 (%8==0)
  int m0 = (nid >> 3) * 128, n0 = (nid & 7) * 128;
  int t = threadIdx.x, wid = t >> 6, l = t & 63, lo = l & 15, hi = l >> 4;
  int wr = wid >> 1, wc = wid & 1;
  __shared__ alignas(16) ushort SMEM[16384];   // 32KB: A dbuf 16KB + B dbuf 16KB
  ushort* ASb = SMEM;                           // AS[b] = ASb + b*4096
  ushort* BSb = SMEM + 8192;                    // BS[b] = BSb + b*4096
  f32x4 acc[4][4];
  f32x4 zf = {0.f, 0.f, 0.f, 0.f};
#pragma unroll
  for (int i = 0; i < 4; i++)
#pragma unroll
    for (int j = 0; j < 4; j++) acc[i][j] = zf;

  // gload_lds slot mapping (T2: per-lane pre-swizzled source, linear dest)
  int sl0 = t, sl1 = 256 + t;
  int r0 = sl0 >> 2, c0 = (sl0 & 3) ^ ((r0 >> 1) & 3);
  int r1 = sl1 >> 2, c1 = (sl1 & 3) ^ ((r1 >> 1) & 3);
  int dst0 = (wid * 64) * 8;          // ushort idx of inst-0 dest base
  int dst1 = (256 + wid * 64) * 8;
  const ushort* gB0 = Bw + (size_t)(n0 + r0) * K + c0 * 8;
  const ushort* gB1 = Bw + (size_t)(n0 + r1) * K + c1 * 8;

  const float*  Af = (const float*)Av;
  const ushort* Ab = (const ushort*)Av;
  int ar = t >> 1, ach = t & 1;                 // fp32 A: row, 16-col half
  const float*  gAf = Af + (size_t)(m0 + ar) * K + ach * 16;
  const ushort* gA0 = Ab + (size_t)(m0 + r0) * K + c0 * 8;
  const ushort* gA1 = Ab + (size_t)(m0 + r1) * K + c1 * 8;
  int awofs = ar * 32;                          // A ds_write row base (ushort)
  int asw = (ar >> 1) & 3;                      // A ds_write chunk swizzle
  float4 av[4];

  // ---- prologue: tile 0 -> buffer 0 ----
  if (AMODE == 0) {
    av[0] = *reinterpret_cast<const float4*>(gAf);
    av[1] = *reinterpret_cast<const float4*>(gAf + 4);
    av[2] = *reinterpret_cast<const float4*>(gAf + 8);
    av[3] = *reinterpret_cast<const float4*>(gAf + 12);
  } else {
    GLD16(gA0, &ASb[dst0]);
    GLD16(gA1, &ASb[dst1]);
  }
  GLD16(gB0, &BSb[dst0]);
  GLD16(gB1, &BSb[dst1]);
  if (AMODE == 0) {
    *reinterpret_cast<short8*>(&ASb[awofs + ((2 * ach) ^ asw) * 8])     = pack2(av[0], av[1]);
    *reinterpret_cast<short8*>(&ASb[awofs + ((2 * ach + 1) ^ asw) * 8]) = pack2(av[2], av[3]);
  }
  asm volatile("s_waitcnt vmcnt(0) lgkmcnt(0)" ::: "memory");
  __builtin_amdgcn_s_barrier();
  FENCE_SCHED();

  const int rsw = (hi ^ ((lo >> 1) & 3)) * 8;   // T2 read: phys chunk offset
  for (int kt = 0; kt < NT; kt++) {
    int cur = kt & 1, nxt = cur ^ 1;
    const ushort* sA = ASb + cur * 4096;
    const ushort* sB = BSb + cur * 4096;
    // (1) issue next tile's loads (latency covered by ds_read+MFMA below)
    if (kt + 1 < NT) {
      int ko = (kt + 1) * 32;
      if (AMODE == 0) {
        av[0] = *reinterpret_cast<const float4*>(gAf + ko);
        av[1] = *reinterpret_cast<const float4*>(gAf + ko + 4);
        av[2] = *reinterpret_cast<const float4*>(gAf + ko + 8);
        av[3] = *reinterpret_cast<const float4*>(gAf + ko + 12);
      } else {
        GLD16(gA0 + ko, &ASb[nxt * 4096 + dst0]);
        GLD16(gA1 + ko, &ASb[nxt * 4096 + dst1]);
      }
      GLD16(gB0 + ko, &BSb[nxt * 4096 + dst0]);
      GLD16(gB1 + ko, &BSb[nxt * 4096 + dst1]);
    }
    FENCE_SCHED();
    // (2) fragments from cur
    short8 af[4], bf_[4];
#pragma unroll
    for (int q = 0; q < 4; q++)
      af[q] = *reinterpret_cast<const short8*>(&sA[(wr * 64 + q * 16 + lo) * 32 + rsw]);
#pragma unroll
    for (int n = 0; n < 4; n++)
      bf_[n] = *reinterpret_cast<const short8*>(&sB[(wc * 64 + n * 16 + lo) * 32 + rsw]);
    // (3) MFMA
    __builtin_amdgcn_s_setprio(1);
#pragma unroll
    for (int q = 0; q < 4; q++)
#pragma unroll
      for (int n = 0; n < 4; n++)
        acc[q][n] = __builtin_amdgcn_mfma_f32_16x16x32_bf16(af[q], bf_[n], acc[q][n], 0, 0, 0);
    __builtin_amdgcn_s_setprio(0);
    // (4) write-late A cvt (compiler waits the av loads)
    if (AMODE == 0 && kt + 1 < NT) {
      *reinterpret_cast<short8*>(&ASb[nxt * 4096 + awofs + ((2 * ach) ^ asw) * 8])     = pack2(av[0], av[1]);
      *reinterpret_cast<short8*>(&ASb[nxt * 4096 + awofs + ((2 * ach + 1) ^ asw) * 8]) = pack2(av[2], av[3]);
    }
    // (5) drain + single barrier (cross-block TLP covers this)
    asm volatile("s_waitcnt vmcnt(0) lgkmcnt(0)" ::: "memory");
    __builtin_amdgcn_s_barrier();
    FENCE_SCHED();
  }

  if constexpr (BIASED) {
    // fp32 + bias, direct (64B-granular segments, no amplification)
    float* C = (float*)Cv;
#pragma unroll
    for (int n = 0; n < 4; n++) {
      int c = n0 + wc * 64 + n * 16 + lo;
      float bv = bias[c];
#pragma unroll
      for (int q = 0; q < 4; q++)
#pragma unroll
        for (int j = 0; j < 4; j++) {
          int r = m0 + wr * 64 + q * 16 + hi * 4 + j;
          C[(size_t)r * 1024 + c] = acc[q][n][j] + bv;
        }
    }
  } else {
    // bf16 via LDS transpose: scattered 2B -> LDS, coalesced 16B -> global
    ushort* C = (ushort*)Cv;
#pragma unroll
    for (int q = 0; q < 4; q++)
#pragma unroll
      for (int n = 0; n < 4; n++)
#pragma unroll
        for (int j = 0; j < 4; j++) {
          int row_l = wr * 64 + q * 16 + hi * 4 + j;
          int col = wc * 64 + n * 16 + lo;
          SMEM[row_l * 128 + (col ^ ((row_l & 7) << 4))] = f2b(acc[q][n][j]);
        }
    __syncthreads();
#pragma unroll
    for (int iter = 0; iter < 8; iter++) {
      int row_l = iter * 16 + (t >> 4), c = t & 15;
      short8 v = *reinterpret_cast<const short8*>(
          &SMEM[row_l * 128 + ((c * 8) ^ ((row_l & 7) << 4))]);
      *reinterpret_cast<short8*>(&C[(size_t)(m0 + row_l) * 1024 + n0 + c * 8]) = v;
    }
  }
}

// --------------------------- 5) attention ----------------------------------
__global__ __launch_bounds__(256) void k_attn(const ushort* __restrict__ Q,
                                              const ushort* __restrict__ Kall,
                                              const ushort* __restrict__ Vt,
                                              ushort* __restrict__ O) {
  int q0 = blockIdx.x * 128, bh = blockIdx.y;
  int b = bh >> 4, h = bh & 15;
  int t = threadIdx.x, w = t >> 6, l = t & 63, lo = l & 15, hi = l >> 4;
  __shared__ alignas(16) ushort P[4][32 * 104];
  const ushort* Qb = Q + ((size_t)b * 4096 + q0 + w * 32) * 1024 + h * 64;
  short8 qf[2][2];
  for (int mi = 0; mi < 2; mi++)
    for (int ks = 0; ks < 2; ks++)
      qf[mi][ks] = *reinterpret_cast<const short8*>(Qb + (size_t)(mi * 16 + lo) * 1024 + ks * 32 + hi * 8);
  const ushort* Kb = Kall + (size_t)bh * 96 * 64;
  f32x4 s[2][6];
  f32x4 zf = {0.f, 0.f, 0.f, 0.f};
  for (int i = 0; i < 2; i++) for (int j = 0; j < 6; j++) s[i][j] = zf;
  for (int ni = 0; ni < 6; ni++)
    for (int ks = 0; ks < 2; ks++) {
      short8 kf = *reinterpret_cast<const short8*>(Kb + (ni * 16 + lo) * 64 + ks * 32 + hi * 8);
      for (int mi = 0; mi < 2; mi++)
        s[mi][ni] = __builtin_amdgcn_mfma_f32_16x16x32_bf16(qf[mi][ks], kf, s[mi][ni], 0, 0, 0);
    }
  const float SC = 0.125f * 1.44269504088896340736f;
  for (int mi = 0; mi < 2; mi++)
    for (int j = 0; j < 4; j++) {
      float pb[5];
      float mb = -1e30f;
      for (int ni = 0; ni < 5; ni++) {
        int c = ni * 16 + lo;
        float v = s[mi][ni][j] * SC;
        pb[ni] = v;
        if (c < 77) mb = fmaxf(mb, v);
      }
      mb = fmaxf(mb, __shfl_xor(mb, 1, 64));
      mb = fmaxf(mb, __shfl_xor(mb, 2, 64));
      mb = fmaxf(mb, __shfl_xor(mb, 4, 64));
      mb = fmaxf(mb, __shfl_xor(mb, 8, 64));
      float sb = 0.f;
      for (int ni = 0; ni < 5; ni++) {
        int c = ni * 16 + lo;
        float p = (c < 77) ? exp2f(pb[ni] - mb) : 0.f;
        pb[ni] = p; sb += p;
      }
      sb += __shfl_xor(sb, 1, 64); sb += __shfl_xor(sb, 2, 64);
      sb += __shfl_xor(sb, 4, 64); sb += __shfl_xor(sb, 8, 64);
      float rb = 1.0f / sb;
      float vip = s[mi][5][j] * SC;
      bool val = lo < 4;
      float mip = val ? vip : -1e30f;
      mip = fmaxf(mip, __shfl_xor(mip, 1, 64));
      mip = fmaxf(mip, __shfl_xor(mip, 2, 64));
      mip = fmaxf(mip, __shfl_xor(mip, 4, 64));
      mip = fmaxf(mip, __shfl_xor(mip, 8, 64));
      float pi = val ? exp2f(vip - mip) : 0.f;
      float si = pi;
      si += __shfl_xor(si, 1, 64); si += __shfl_xor(si, 2, 64);
      si += __shfl_xor(si, 4, 64); si += __shfl_xor(si, 8, 64);
      float ri = 1.0f / si;
      int row = mi * 16 + hi * 4 + j;
      ushort* pr = &P[w][row * 104];
      for (int ni = 0; ni < 5; ni++) pr[ni * 16 + lo] = f2b(pb[ni] * rb);
      pr[80 + lo] = f2b(pi * ri);
    }
  __syncthreads();
  f32x4 o[2][4];
  for (int i = 0; i < 2; i++) for (int j = 0; j < 4; j++) o[i][j] = zf;
  const ushort* Vb = Vt + (size_t)bh * 64 * 96;
  for (int kk = 0; kk < 3; kk++) {
    short8 pf[2];
    for (int mi = 0; mi < 2; mi++)
      pf[mi] = *reinterpret_cast<const short8*>(&P[w][(mi * 16 + lo) * 104 + kk * 32 + hi * 8]);
    for (int dn = 0; dn < 4; dn++) {
      short8 vf = *reinterpret_cast<const short8*>(Vb + (dn * 16 + lo) * 96 + kk * 32 + hi * 8);
      for (int mi = 0; mi < 2; mi++)
        o[mi][dn] = __builtin_amdgcn_mfma_f32_16x16x32_bf16(pf[mi], vf, o[mi][dn], 0, 0, 0);
    }
  }
  ushort* Ob = O + ((size_t)b * 4096 + q0 + w * 32) * 1024 + h * 64;
  for (int mi = 0; mi < 2; mi++)
    for (int dn = 0; dn < 4; dn++)
      for (int j = 0; j < 4; j++)
        Ob[(size_t)(mi * 16 + hi * 4 + j) * 1024 + dn * 16 + lo] = f2b(o[mi][dn][j]);
}

// ---------------------------------------------------------------------------
extern "C" void kernel_launch(void* const* d_in, const int* in_sizes, int n_in,
                              void* d_out, int out_size, void* d_ws, size_t ws_size,
                              hipStream_t stream) {
  const float* hs   = (const float*)d_in[0];
  const float* enc  = (const float*)d_in[1];
  const float* Wq   = (const float*)d_in[2];
  const float* Wk   = (const float*)d_in[3];
  const float* Wv   = (const float*)d_in[4];
  const float* Wkip = (const float*)d_in[5];
  const float* Wvip = (const float*)d_in[6];
  const float* Wo   = (const float*)d_in[7];
  const float* bo   = (const float*)d_in[8];
  const float* lnw  = (const float*)d_in[9];
  const float* lnb  = (const float*)d_in[10];
  float* out = (float*)d_out;
  ushort* Qbuf = (ushort*)d_out;  // bf16 Q parked in first 64MB of the 128MB output

  ushort* p = (ushort*)d_ws;
  ushort* attn    = p; p += (size_t)32768 * 1024;
  ushort* wq_bf   = p; p += (size_t)1024 * 1024;
  ushort* wo_bf   = p; p += (size_t)1024 * 1024;
  ushort* wk_bf   = p; p += (size_t)1024 * 768;
  ushort* wkip_bf = p; p += (size_t)1024 * 768;
  ushort* wv_bf   = p; p += (size_t)1024 * 768;
  ushort* wvip_bf = p; p += (size_t)1024 * 768;
  ushort* xn      = p; p += (size_t)8 * 96 * 768;
  ushort* kall    = p; p += (size_t)8 * 16 * 96 * 64;
  ushort* vtall   = p; p += (size_t)8 * 16 * 96 * 64;

  CvtArgs ca;
  ca.src[0] = Wq;   ca.dst[0] = wq_bf;   ca.n4[0] = 262144;
  ca.src[1] = Wo;   ca.dst[1] = wo_bf;   ca.n4[1] = 262144;
  ca.src[2] = Wk;   ca.dst[2] = wk_bf;   ca.n4[2] = 196608;
  ca.src[3] = Wkip; ca.dst[3] = wkip_bf; ca.n4[3] = 196608;
  ca.src[4] = Wv;   ca.dst[4] = wv_bf;   ca.n4[4] = 196608;
  ca.src[5] = Wvip; ca.dst[5] = wvip_bf; ca.n4[5] = 196608;
  k_cvt_all<<<dim3(1024, 6), 256, 0, stream>>>(ca);
  k_build_xn<<<dim3(96, 8), 256, 0, stream>>>(enc, lnw, lnb, xn);
  k_kv<<<dim3(4, 8), 256, 0, stream>>>(xn, wk_bf, wkip_bf, kall, 0);
  k_kv<<<dim3(4, 8), 256, 0, stream>>>(xn, wv_bf, wvip_bf, vtall, 1);
  k_gemm32<0, false><<<2048, 256, 0, stream>>>((const void*)hs, wq_bf, nullptr, (void*)Qbuf);
  k_attn<<<dim3(32, 128), 256, 0, stream>>>(Qbuf, kall, vtall, attn);
  k_gemm32<1, true><<<2048, 256, 0, stream>>>((const void*)attn, wo_bf, bo, (void*)out);
}

// Round 8
// 409.744 us; speedup vs baseline: 1.0687x; 1.0687x over previous
//
#include <hip/hip_runtime.h>
#include <hip/hip_bf16.h>
#include <stdint.h>

// ---------------------------------------------------------------------------
// CrossViewIPAttnProcessor on MI355X (gfx950)
// B=8, Lq=4096, D=1024, Dc=768, H=16, HD=64, text=77 keys, ip=4 keys
// Round 8: R7 + one-line fix: guard the ip-softmax P write for masked lanes
// (lanes lo>=4 had si=0 -> ri=inf -> 0*inf=NaN -> propagated via PV MFMA).
// ---------------------------------------------------------------------------

typedef __attribute__((ext_vector_type(8))) short short8;
typedef __attribute__((ext_vector_type(4))) float f32x4;
typedef __attribute__((ext_vector_type(8))) float float8_t;
typedef __attribute__((ext_vector_type(8))) __bf16 bf16x8;
typedef __attribute__((ext_vector_type(4))) __bf16 bf16x4;

__device__ __forceinline__ ushort f2b(float f) {
  __bf16 h = (__bf16)f;
  return __builtin_bit_cast(ushort, h);
}

__device__ __forceinline__ short8 pack2(float4 a, float4 b) {
  float8_t v;
  v[0] = a.x; v[1] = a.y; v[2] = a.z; v[3] = a.w;
  v[4] = b.x; v[5] = b.y; v[6] = b.z; v[7] = b.w;
  return __builtin_bit_cast(short8, __builtin_convertvector(v, bf16x8));
}

#define GLD16(gp, lp) \
  __builtin_amdgcn_global_load_lds((const __attribute__((address_space(1))) uint32_t*)(gp), \
                                   (__attribute__((address_space(3))) uint32_t*)(lp), 16, 0, 0)

#define FENCE_SCHED() __builtin_amdgcn_sched_barrier(0)

// --------------------- 1) fused fp32 -> bf16 for 6 weights ------------------
struct CvtArgs {
  const float* src[6];
  ushort* dst[6];
  int n4[6];
};

__global__ __launch_bounds__(256) void k_cvt_all(CvtArgs a) {
  int seg = blockIdx.y;
  int i = blockIdx.x * blockDim.x + threadIdx.x;
  if (i >= a.n4[seg]) return;
  float4 v = reinterpret_cast<const float4*>(a.src[seg])[i];
  bf16x4 h;
  h[0] = (__bf16)v.x; h[1] = (__bf16)v.y; h[2] = (__bf16)v.z; h[3] = (__bf16)v.w;
  reinterpret_cast<ushort4*>(a.dst[seg])[i] = __builtin_bit_cast(ushort4, h);
}

// --------------------------- 2) Xn builder ---------------------------------
__global__ __launch_bounds__(256) void k_build_xn(const float* __restrict__ enc,
                                                  const float* __restrict__ lnw,
                                                  const float* __restrict__ lnb,
                                                  ushort* __restrict__ xn) {
  const int Dc = 768;
  int tok = blockIdx.x, b = blockIdx.y, t = threadIdx.x;
  ushort* out = xn + ((size_t)b * 96 + tok) * Dc;
  bool padrow = (tok >= 84) || (tok >= 77 && tok < 80);
  if (padrow) { out[t] = 0; out[t + 256] = 0; out[t + 512] = 0; return; }
  const float* src = (tok < 77) ? enc + ((size_t)b * 81 + tok) * Dc
                                : enc + ((size_t)b * 81 + 77 + (tok - 80)) * Dc;
  float x0 = src[t], x1 = src[t + 256], x2 = src[t + 512];
  if (tok >= 80) { out[t] = f2b(x0); out[t + 256] = f2b(x1); out[t + 512] = f2b(x2); return; }
  float s = x0 + x1 + x2, q = x0 * x0 + x1 * x1 + x2 * x2;
  for (int m = 32; m; m >>= 1) { s += __shfl_xor(s, m, 64); q += __shfl_xor(q, m, 64); }
  __shared__ float rs[4], rq[4];
  int w = t >> 6;
  if ((t & 63) == 0) { rs[w] = s; rq[w] = q; }
  __syncthreads();
  s = rs[0] + rs[1] + rs[2] + rs[3];
  q = rq[0] + rq[1] + rq[2] + rq[3];
  float mean = s * (1.0f / 768.0f);
  float var = q * (1.0f / 768.0f) - mean * mean;
  float rstd = rsqrtf(var + 1e-5f);
  out[t]       = f2b((x0 - mean) * rstd * lnw[t]       + lnb[t]);
  out[t + 256] = f2b((x1 - mean) * rstd * lnw[t + 256] + lnb[t + 256]);
  out[t + 512] = f2b((x2 - mean) * rstd * lnw[t + 512] + lnb[t + 512]);
}

// --------------------------- 3) K/V projection -----------------------------
__global__ __launch_bounds__(256) void k_kv(const ushort* __restrict__ xn,
                                            const ushort* __restrict__ wb,
                                            const ushort* __restrict__ wipb,
                                            ushort* __restrict__ out, int mode) {
  int n0 = blockIdx.x * 256, b = blockIdx.y;
  int t = threadIdx.x, w = t >> 6, l = t & 63, lo = l & 15, hi = l >> 4;
  __shared__ alignas(16) ushort Xs[96 * 32];
  __shared__ alignas(16) ushort Ws[256 * 32];
  __shared__ alignas(16) ushort Wip[256 * 32];
  f32x4 acc[6][4];
  f32x4 zf = {0.f, 0.f, 0.f, 0.f};
  for (int i = 0; i < 6; i++) for (int j = 0; j < 4; j++) acc[i][j] = zf;
  const ushort* xb = xn + (size_t)b * 96 * 768;
  for (int k0 = 0; k0 < 768; k0 += 32) {
    __syncthreads();
    for (int i = t; i < 96 * 16; i += 256) {
      int row = i >> 4, p = i & 15;
      reinterpret_cast<uint32_t*>(Xs)[i] =
          *reinterpret_cast<const uint32_t*>(xb + row * 768 + k0 + p * 2);
    }
    for (int i = t; i < 256 * 16; i += 256) {
      int row = i >> 4, p = i & 15;
      reinterpret_cast<uint32_t*>(Ws)[i] =
          *reinterpret_cast<const uint32_t*>(wb + (size_t)(n0 + row) * 768 + k0 + p * 2);
      reinterpret_cast<uint32_t*>(Wip)[i] =
          *reinterpret_cast<const uint32_t*>(wipb + (size_t)(n0 + row) * 768 + k0 + p * 2);
    }
    __syncthreads();
    short8 a[6], bb[4], bip[4];
    for (int mi = 0; mi < 6; mi++)
      a[mi] = *reinterpret_cast<const short8*>(Xs + (mi * 16 + lo) * 32 + hi * 8);
    for (int ni = 0; ni < 4; ni++) {
      bb[ni]  = *reinterpret_cast<const short8*>(Ws  + (w * 64 + ni * 16 + lo) * 32 + hi * 8);
      bip[ni] = *reinterpret_cast<const short8*>(Wip + (w * 64 + ni * 16 + lo) * 32 + hi * 8);
    }
    for (int ni = 0; ni < 4; ni++) {
      for (int mi = 0; mi < 5; mi++)
        acc[mi][ni] = __builtin_amdgcn_mfma_f32_16x16x32_bf16(a[mi], bb[ni], acc[mi][ni], 0, 0, 0);
      acc[5][ni] = __builtin_amdgcn_mfma_f32_16x16x32_bf16(a[5], bip[ni], acc[5][ni], 0, 0, 0);
    }
  }
  for (int mi = 0; mi < 6; mi++)
    for (int ni = 0; ni < 4; ni++) {
      int col = n0 + w * 64 + ni * 16 + lo;
      int h = col >> 6, dd = col & 63;
      for (int j = 0; j < 4; j++) {
        int tok = mi * 16 + hi * 4 + j;
        ushort v = f2b(acc[mi][ni][j]);
        if (mode == 0) out[(((size_t)b * 16 + h) * 96 + tok) * 64 + dd] = v;
        else           out[(((size_t)b * 16 + h) * 64 + dd) * 96 + tok] = v;
      }
    }
}

// ------------------- 4) Q GEMM: 8-phase, fp32 A reg-staged -----------------
// C[32768][1024] bf16 = A[32768][1024] fp32 @ Bw^T bf16. 256x256, BK=64,
// 8 waves. A: av loads @p0, ds_write @p2/p3 (in-order vmcnt keeps B deep).
// B: gload_lds 2 tiles ahead, vmcnt(4) @p3. bf16 C via LDS epilogue.
__global__ __launch_bounds__(512, 2) void k_qg8(const float* __restrict__ A,
                                                const ushort* __restrict__ Bw,
                                                ushort* __restrict__ C) {
  const int K = 1024, NT = 16;
  int wg = blockIdx.x;
  int nid = (wg & 7) * 64 + (wg >> 3);      // XCD-chunked, nwg=512 (%8==0)
  int m0 = (nid >> 2) * 256, n0 = (nid & 3) * 256;
  int t = threadIdx.x, wid = t >> 6, l = t & 63, lo = l & 15, hi = l >> 4;
  int wr = wid >> 2, wc = wid & 3;
  __shared__ alignas(16) ushort SMEM[65536];        // 128KB
  ushort* ASb = SMEM;                                // AS[b] = +b*16384
  ushort* BSb = SMEM + 32768;                        // BS[b] = +b*16384
  f32x4 acc[8][4];
  f32x4 zf = {0.f, 0.f, 0.f, 0.f};
#pragma unroll
  for (int i = 0; i < 8; i++)
#pragma unroll
    for (int j = 0; j < 4; j++) acc[i][j] = zf;
  int tr = t >> 3, tc = t & 7;
  int tcs = tc ^ (tr & 7);                  // T2 pre-swizzled source chunk
  const float*  gA = A  + (size_t)(m0 + tr) * K + tcs * 8;
  const ushort* gB = Bw + (size_t)(n0 + tr) * K + tcs * 8;
  float4 av[4][2];

#define LD_A(kt_) do { \
    _Pragma("unroll") \
    for (int s = 0; s < 4; s++) { \
      av[s][0] = *reinterpret_cast<const float4*>(gA + (size_t)s * 64 * K + (kt_) * 64); \
      av[s][1] = *reinterpret_cast<const float4*>(gA + (size_t)s * 64 * K + (kt_) * 64 + 4); \
    } } while (0)
#define WR_A(s_, b_) \
    *reinterpret_cast<short8*>(&ASb[(b_) * 16384 + (s_) * 4096 + t * 8]) = pack2(av[s_][0], av[s_][1])
#define STG_B(kt_, s_, b_) GLD16(gB + (size_t)(s_) * 64 * K + (kt_) * 64, &BSb[(b_) * 16384 + (s_) * 4096 + wid * 512])

  // ---- prologue ----
  LD_A(0);
  STG_B(0, 0, 0); STG_B(0, 1, 0); STG_B(0, 2, 0); STG_B(0, 3, 0);
  STG_B(1, 0, 1); STG_B(1, 1, 1); STG_B(1, 2, 1); STG_B(1, 3, 1);
  WR_A(0, 0); WR_A(1, 0); WR_A(2, 0); WR_A(3, 0);
  LD_A(1);
  WR_A(0, 1); WR_A(1, 1); WR_A(2, 1); WR_A(3, 1);   // implicit waits drain B(0),B(1) too (one-time)
  asm volatile("s_waitcnt lgkmcnt(0)" ::: "memory");
  __builtin_amdgcn_s_barrier();
  FENCE_SCHED();

  const int swz = (lo & 7) << 3;
  short8 af[4][2], af2[4][2], b01[2][2], b23[2][2];

  for (int kt = 0; kt < NT; kt++) {
    int cur = kt & 1, nxt = cur ^ 1;
    const ushort* sA = &ASb[cur * 16384];
    const ushort* sB = &BSb[cur * 16384];
    // ========== phase 0: av loads (A(t+1)); af + b01 reads; MFMA q03xn01 ===
    if (kt + 1 < NT) LD_A(kt + 1);
#pragma unroll
    for (int q = 0; q < 4; q++)
#pragma unroll
      for (int kk = 0; kk < 2; kk++)
        af[q][kk] = *reinterpret_cast<const short8*>(
            sA + (wr * 128 + q * 16 + lo) * 64 + ((hi * 8 + kk * 32) ^ swz));
#pragma unroll
    for (int n = 0; n < 2; n++)
#pragma unroll
      for (int kk = 0; kk < 2; kk++)
        b01[n][kk] = *reinterpret_cast<const short8*>(
            sB + (wc * 64 + n * 16 + lo) * 64 + ((hi * 8 + kk * 32) ^ swz));
    __builtin_amdgcn_s_barrier();
    FENCE_SCHED();
    __builtin_amdgcn_s_setprio(1);
#pragma unroll
    for (int q = 0; q < 4; q++)
#pragma unroll
      for (int n = 0; n < 2; n++)
#pragma unroll
        for (int kk = 0; kk < 2; kk++)
          acc[q][n] = __builtin_amdgcn_mfma_f32_16x16x32_bf16(af[q][kk], b01[n][kk], acc[q][n], 0, 0, 0);
    __builtin_amdgcn_s_setprio(0);
    __builtin_amdgcn_s_barrier();
    FENCE_SCHED();
    // ========== phase 1: b23 reads; MFMA q03xn23 ==========================
#pragma unroll
    for (int n = 0; n < 2; n++)
#pragma unroll
      for (int kk = 0; kk < 2; kk++)
        b23[n][kk] = *reinterpret_cast<const short8*>(
            sB + (wc * 64 + (2 + n) * 16 + lo) * 64 + ((hi * 8 + kk * 32) ^ swz));
    __builtin_amdgcn_s_barrier();
    FENCE_SCHED();
    __builtin_amdgcn_s_setprio(1);
#pragma unroll
    for (int q = 0; q < 4; q++)
#pragma unroll
      for (int n = 0; n < 2; n++)
#pragma unroll
        for (int kk = 0; kk < 2; kk++)
          acc[q][2 + n] = __builtin_amdgcn_mfma_f32_16x16x32_bf16(af[q][kk], b23[n][kk], acc[q][2 + n], 0, 0, 0);
    __builtin_amdgcn_s_setprio(0);
    __builtin_amdgcn_s_barrier();
    FENCE_SCHED();
    // ========== phase 2: af2 reads; B(t+2) s01 glds; A(t+1) s01 writes;
    //            MFMA q47xn23 ============================================
#pragma unroll
    for (int q = 0; q < 4; q++)
#pragma unroll
      for (int kk = 0; kk < 2; kk++)
        af2[q][kk] = *reinterpret_cast<const short8*>(
            sA + (wr * 128 + (4 + q) * 16 + lo) * 64 + ((hi * 8 + kk * 32) ^ swz));
    if (kt + 2 < NT) { STG_B(kt + 2, 0, cur); STG_B(kt + 2, 1, cur); }
    if (kt + 1 < NT) { WR_A(0, nxt); WR_A(1, nxt); }  // implicit wait retires av01 + B(t+1)
    asm volatile("s_waitcnt lgkmcnt(0)" ::: "memory");
    __builtin_amdgcn_s_barrier();
    FENCE_SCHED();
    __builtin_amdgcn_s_setprio(1);
#pragma unroll
    for (int q = 0; q < 4; q++)
#pragma unroll
      for (int n = 0; n < 2; n++)
#pragma unroll
        for (int kk = 0; kk < 2; kk++)
          acc[4 + q][2 + n] = __builtin_amdgcn_mfma_f32_16x16x32_bf16(af2[q][kk], b23[n][kk], acc[4 + q][2 + n], 0, 0, 0);
    __builtin_amdgcn_s_setprio(0);
    __builtin_amdgcn_s_barrier();
    FENCE_SCHED();
    // ========== phase 3: B(t+2) s23 glds; A(t+1) s23 writes; vmcnt(4);
    //            MFMA q47xn01 ============================================
    if (kt + 2 < NT) { STG_B(kt + 2, 2, cur); STG_B(kt + 2, 3, cur); }
    if (kt + 1 < NT) { WR_A(2, nxt); WR_A(3, nxt); }
    asm volatile("s_waitcnt vmcnt(4)" ::: "memory");
    asm volatile("s_waitcnt lgkmcnt(0)" ::: "memory");
    __builtin_amdgcn_s_barrier();
    FENCE_SCHED();
    __builtin_amdgcn_s_setprio(1);
#pragma unroll
    for (int q = 0; q < 4; q++)
#pragma unroll
      for (int n = 0; n < 2; n++)
#pragma unroll
        for (int kk = 0; kk < 2; kk++)
          acc[4 + q][n] = __builtin_amdgcn_mfma_f32_16x16x32_bf16(af2[q][kk], b01[n][kk], acc[4 + q][n], 0, 0, 0);
    __builtin_amdgcn_s_setprio(0);
    __builtin_amdgcn_s_barrier();
    FENCE_SCHED();
  }
  // ---- epilogue: per-wave LDS transpose, coalesced bf16 stores ----
  __syncthreads();
  ushort* ep = SMEM + wid * 8192;          // 16KB per wave (128 rows x 64 cols)
#pragma unroll
  for (int mi = 0; mi < 8; mi++)
#pragma unroll
    for (int n = 0; n < 4; n++)
#pragma unroll
      for (int j = 0; j < 4; j++) {
        int row_l = mi * 16 + hi * 4 + j;
        int col = n * 16 + lo;
        ep[row_l * 64 + (((col >> 3) ^ (row_l & 7)) << 3) + (col & 7)] = f2b(acc[mi][n][j]);
      }
  asm volatile("s_waitcnt lgkmcnt(0)" ::: "memory");
#pragma unroll
  for (int it = 0; it < 16; it++) {
    int row_l = it * 8 + (l >> 3), ch = l & 7;
    short8 v = *reinterpret_cast<const short8*>(&ep[row_l * 64 + ((ch ^ (row_l & 7)) << 3)]);
    *reinterpret_cast<short8*>(&C[(size_t)(m0 + wr * 128 + row_l) * 1024 + n0 + wc * 64 + ch * 8]) = v;
  }
#undef LD_A
#undef WR_A
#undef STG_B
}

// ------------------- 6) out GEMM: R5 8-phase, bf16 A, fp32 C + bias --------
__global__ __launch_bounds__(512, 2) void k_og8(const ushort* __restrict__ A,
                                                const ushort* __restrict__ Bw,
                                                const float* __restrict__ bias,
                                                float* __restrict__ C) {
  const int K = 1024, NT = 16;
  int wg = blockIdx.x;
  int nid = (wg & 7) * 64 + (wg >> 3);
  int m0 = (nid >> 2) * 256, n0 = (nid & 3) * 256;
  int t = threadIdx.x, wid = t >> 6, l = t & 63, lo = l & 15, hi = l >> 4;
  int wr = wid >> 2, wc = wid & 3;
  __shared__ alignas(16) ushort AS[2][256 * 64];
  __shared__ alignas(16) ushort BS[2][256 * 64];
  f32x4 acc[8][4];
  f32x4 zf = {0.f, 0.f, 0.f, 0.f};
#pragma unroll
  for (int i = 0; i < 8; i++)
#pragma unroll
    for (int j = 0; j < 4; j++) acc[i][j] = zf;
  int tr = t >> 3, tc = t & 7;
  int tcs = tc ^ (tr & 7);
  const ushort* gA = A  + (size_t)(m0 + tr) * K + tcs * 8;
  const ushort* gB = Bw + (size_t)(n0 + tr) * K + tcs * 8;

#define STG_A(kt_, s_, b_) GLD16(gA + (size_t)(s_) * 64 * K + (kt_) * 64, &AS[b_][(s_) * 4096 + wid * 512])
#define STG_B(kt_, s_, b_) GLD16(gB + (size_t)(s_) * 64 * K + (kt_) * 64, &BS[b_][(s_) * 4096 + wid * 512])

  STG_A(0, 0, 0); STG_A(0, 1, 0); STG_A(0, 2, 0); STG_A(0, 3, 0);
  STG_B(0, 0, 0); STG_B(0, 1, 0); STG_B(0, 2, 0); STG_B(0, 3, 0);
  STG_B(1, 0, 1); STG_B(1, 1, 1); STG_B(1, 2, 1); STG_B(1, 3, 1);
  STG_A(1, 0, 1); STG_A(1, 1, 1);
  asm volatile("s_waitcnt vmcnt(6)" ::: "memory");
  __builtin_amdgcn_s_barrier();
  FENCE_SCHED();

  const int swz = (lo & 7) << 3;
  short8 af[4][2], af2[4][2], b01[2][2], b23[2][2];

  for (int kt = 0; kt < NT; kt++) {
    int cur = kt & 1, nxt = cur ^ 1;
    const ushort* sA = &AS[cur][0];
    const ushort* sB = &BS[cur][0];
    // phase 0
#pragma unroll
    for (int q = 0; q < 4; q++)
#pragma unroll
      for (int kk = 0; kk < 2; kk++)
        af[q][kk] = *reinterpret_cast<const short8*>(
            sA + (wr * 128 + q * 16 + lo) * 64 + ((hi * 8 + kk * 32) ^ swz));
#pragma unroll
    for (int n = 0; n < 2; n++)
#pragma unroll
      for (int kk = 0; kk < 2; kk++)
        b01[n][kk] = *reinterpret_cast<const short8*>(
            sB + (wc * 64 + n * 16 + lo) * 64 + ((hi * 8 + kk * 32) ^ swz));
    if (kt + 1 < NT) { STG_A(kt + 1, 2, nxt); STG_A(kt + 1, 3, nxt); }
    __builtin_amdgcn_s_barrier();
    FENCE_SCHED();
    __builtin_amdgcn_s_setprio(1);
#pragma unroll
    for (int q = 0; q < 4; q++)
#pragma unroll
      for (int n = 0; n < 2; n++)
#pragma unroll
        for (int kk = 0; kk < 2; kk++)
          acc[q][n] = __builtin_amdgcn_mfma_f32_16x16x32_bf16(af[q][kk], b01[n][kk], acc[q][n], 0, 0, 0);
    __builtin_amdgcn_s_setprio(0);
    __builtin_amdgcn_s_barrier();
    FENCE_SCHED();
    // phase 1
#pragma unroll
    for (int n = 0; n < 2; n++)
#pragma unroll
      for (int kk = 0; kk < 2; kk++)
        b23[n][kk] = *reinterpret_cast<const short8*>(
            sB + (wc * 64 + (2 + n) * 16 + lo) * 64 + ((hi * 8 + kk * 32) ^ swz));
    __builtin_amdgcn_s_barrier();
    FENCE_SCHED();
    __builtin_amdgcn_s_setprio(1);
#pragma unroll
    for (int q = 0; q < 4; q++)
#pragma unroll
      for (int n = 0; n < 2; n++)
#pragma unroll
        for (int kk = 0; kk < 2; kk++)
          acc[q][2 + n] = __builtin_amdgcn_mfma_f32_16x16x32_bf16(af[q][kk], b23[n][kk], acc[q][2 + n], 0, 0, 0);
    __builtin_amdgcn_s_setprio(0);
    __builtin_amdgcn_s_barrier();
    FENCE_SCHED();
    // phase 2
#pragma unroll
    for (int q = 0; q < 4; q++)
#pragma unroll
      for (int kk = 0; kk < 2; kk++)
        af2[q][kk] = *reinterpret_cast<const short8*>(
            sA + (wr * 128 + (4 + q) * 16 + lo) * 64 + ((hi * 8 + kk * 32) ^ swz));
    if (kt + 2 < NT) { STG_B(kt + 2, 0, cur); STG_B(kt + 2, 1, cur); }
    __builtin_amdgcn_s_barrier();
    FENCE_SCHED();
    __builtin_amdgcn_s_setprio(1);
#pragma unroll
    for (int q = 0; q < 4; q++)
#pragma unroll
      for (int n = 0; n < 2; n++)
#pragma unroll
        for (int kk = 0; kk < 2; kk++)
          acc[4 + q][2 + n] = __builtin_amdgcn_mfma_f32_16x16x32_bf16(af2[q][kk], b23[n][kk], acc[4 + q][2 + n], 0, 0, 0);
    __builtin_amdgcn_s_setprio(0);
    __builtin_amdgcn_s_barrier();
    FENCE_SCHED();
    // phase 3
    if (kt + 2 < NT) {
      STG_B(kt + 2, 2, cur); STG_B(kt + 2, 3, cur);
      STG_A(kt + 2, 0, cur); STG_A(kt + 2, 1, cur);
      asm volatile("s_waitcnt vmcnt(6)" ::: "memory");
    } else {
      asm volatile("s_waitcnt vmcnt(0)" ::: "memory");
    }
    __builtin_amdgcn_s_barrier();
    FENCE_SCHED();
    __builtin_amdgcn_s_setprio(1);
#pragma unroll
    for (int q = 0; q < 4; q++)
#pragma unroll
      for (int n = 0; n < 2; n++)
#pragma unroll
        for (int kk = 0; kk < 2; kk++)
          acc[4 + q][n] = __builtin_amdgcn_mfma_f32_16x16x32_bf16(af2[q][kk], b01[n][kk], acc[4 + q][n], 0, 0, 0);
    __builtin_amdgcn_s_setprio(0);
    __builtin_amdgcn_s_barrier();
    FENCE_SCHED();
  }
#pragma unroll
  for (int n = 0; n < 4; n++) {
    int c = n0 + wc * 64 + n * 16 + lo;
    float bv = bias[c];
#pragma unroll
    for (int mi = 0; mi < 8; mi++)
#pragma unroll
      for (int j = 0; j < 4; j++) {
        int r = m0 + wr * 128 + mi * 16 + hi * 4 + j;
        C[(size_t)r * 1024 + c] = acc[mi][n][j] + bv;
      }
  }
#undef STG_A
#undef STG_B
}

// --------------------------- 5) attention ----------------------------------
__global__ __launch_bounds__(256) void k_attn(const ushort* __restrict__ Q,
                                              const ushort* __restrict__ Kall,
                                              const ushort* __restrict__ Vt,
                                              ushort* __restrict__ O) {
  int q0 = blockIdx.x * 128, bh = blockIdx.y;
  int b = bh >> 4, h = bh & 15;
  int t = threadIdx.x, w = t >> 6, l = t & 63, lo = l & 15, hi = l >> 4;
  __shared__ alignas(16) ushort P[4][32 * 104];
  const ushort* Qb = Q + ((size_t)b * 4096 + q0 + w * 32) * 1024 + h * 64;
  short8 qf[2][2];
  for (int mi = 0; mi < 2; mi++)
    for (int ks = 0; ks < 2; ks++)
      qf[mi][ks] = *reinterpret_cast<const short8*>(Qb + (size_t)(mi * 16 + lo) * 1024 + ks * 32 + hi * 8);
  const ushort* Kb = Kall + (size_t)bh * 96 * 64;
  f32x4 s[2][6];
  f32x4 zf = {0.f, 0.f, 0.f, 0.f};
  for (int i = 0; i < 2; i++) for (int j = 0; j < 6; j++) s[i][j] = zf;
  for (int ni = 0; ni < 6; ni++)
    for (int ks = 0; ks < 2; ks++) {
      short8 kf = *reinterpret_cast<const short8*>(Kb + (ni * 16 + lo) * 64 + ks * 32 + hi * 8);
      for (int mi = 0; mi < 2; mi++)
        s[mi][ni] = __builtin_amdgcn_mfma_f32_16x16x32_bf16(qf[mi][ks], kf, s[mi][ni], 0, 0, 0);
    }
  const float SC = 0.125f * 1.44269504088896340736f;
  for (int mi = 0; mi < 2; mi++)
    for (int j = 0; j < 4; j++) {
      float pb[5];
      float mb = -1e30f;
      for (int ni = 0; ni < 5; ni++) {
        int c = ni * 16 + lo;
        float v = s[mi][ni][j] * SC;
        pb[ni] = v;
        if (c < 77) mb = fmaxf(mb, v);
      }
      mb = fmaxf(mb, __shfl_xor(mb, 1, 64));
      mb = fmaxf(mb, __shfl_xor(mb, 2, 64));
      mb = fmaxf(mb, __shfl_xor(mb, 4, 64));
      mb = fmaxf(mb, __shfl_xor(mb, 8, 64));
      float sb = 0.f;
      for (int ni = 0; ni < 5; ni++) {
        int c = ni * 16 + lo;
        float p = (c < 77) ? exp2f(pb[ni] - mb) : 0.f;
        pb[ni] = p; sb += p;
      }
      sb += __shfl_xor(sb, 1, 64); sb += __shfl_xor(sb, 2, 64);
      sb += __shfl_xor(sb, 4, 64); sb += __shfl_xor(sb, 8, 64);
      float rb = 1.0f / sb;
      // ip softmax: lanes lo<4 hold cols 80..83; 2 shfl levels reduce the
      // aligned 4-lane group. Masked lanes have si==0 -> MUST NOT compute
      // pi*ri there (0*inf=NaN, propagates through PV MFMA even vs zero V).
      float vip = s[mi][5][j] * SC;
      bool val = lo < 4;
      float mip = val ? vip : -1e30f;
      mip = fmaxf(mip, __shfl_xor(mip, 1, 64));
      mip = fmaxf(mip, __shfl_xor(mip, 2, 64));
      float pi = val ? exp2f(vip - mip) : 0.f;
      float si = pi;
      si += __shfl_xor(si, 1, 64); si += __shfl_xor(si, 2, 64);
      float ri = 1.0f / si;
      int row = mi * 16 + hi * 4 + j;
      ushort* pr = &P[w][row * 104];
      for (int ni = 0; ni < 5; ni++) pr[ni * 16 + lo] = f2b(pb[ni] * rb);
      pr[80 + lo] = f2b(val ? pi * ri : 0.f);
    }
  __syncthreads();
  f32x4 o[2][4];
  for (int i = 0; i < 2; i++) for (int j = 0; j < 4; j++) o[i][j] = zf;
  const ushort* Vb = Vt + (size_t)bh * 64 * 96;
  for (int kk = 0; kk < 3; kk++) {
    short8 pf[2];
    for (int mi = 0; mi < 2; mi++)
      pf[mi] = *reinterpret_cast<const short8*>(&P[w][(mi * 16 + lo) * 104 + kk * 32 + hi * 8]);
    for (int dn = 0; dn < 4; dn++) {
      short8 vf = *reinterpret_cast<const short8*>(Vb + (dn * 16 + lo) * 96 + kk * 32 + hi * 8);
      for (int mi = 0; mi < 2; mi++)
        o[mi][dn] = __builtin_amdgcn_mfma_f32_16x16x32_bf16(pf[mi], vf, o[mi][dn], 0, 0, 0);
    }
  }
  ushort* Ob = O + ((size_t)b * 4096 + q0 + w * 32) * 1024 + h * 64;
  for (int mi = 0; mi < 2; mi++)
    for (int dn = 0; dn < 4; dn++)
      for (int j = 0; j < 4; j++)
        Ob[(size_t)(mi * 16 + hi * 4 + j) * 1024 + dn * 16 + lo] = f2b(o[mi][dn][j]);
}

// ---------------------------------------------------------------------------
extern "C" void kernel_launch(void* const* d_in, const int* in_sizes, int n_in,
                              void* d_out, int out_size, void* d_ws, size_t ws_size,
                              hipStream_t stream) {
  const float* hs   = (const float*)d_in[0];
  const float* enc  = (const float*)d_in[1];
  const float* Wq   = (const float*)d_in[2];
  const float* Wk   = (const float*)d_in[3];
  const float* Wv   = (const float*)d_in[4];
  const float* Wkip = (const float*)d_in[5];
  const float* Wvip = (const float*)d_in[6];
  const float* Wo   = (const float*)d_in[7];
  const float* bo   = (const float*)d_in[8];
  const float* lnw  = (const float*)d_in[9];
  const float* lnb  = (const float*)d_in[10];
  float* out = (float*)d_out;
  ushort* Qbuf = (ushort*)d_out;  // bf16 Q parked in first 64MB of the 128MB output

  ushort* p = (ushort*)d_ws;
  ushort* attn    = p; p += (size_t)32768 * 1024;
  ushort* wq_bf   = p; p += (size_t)1024 * 1024;
  ushort* wo_bf   = p; p += (size_t)1024 * 1024;
  ushort* wk_bf   = p; p += (size_t)1024 * 768;
  ushort* wkip_bf = p; p += (size_t)1024 * 768;
  ushort* wv_bf   = p; p += (size_t)1024 * 768;
  ushort* wvip_bf = p; p += (size_t)1024 * 768;
  ushort* xn      = p; p += (size_t)8 * 96 * 768;
  ushort* kall    = p; p += (size_t)8 * 16 * 96 * 64;
  ushort* vtall   = p; p += (size_t)8 * 16 * 96 * 64;

  CvtArgs ca;
  ca.src[0] = Wq;   ca.dst[0] = wq_bf;   ca.n4[0] = 262144;
  ca.src[1] = Wo;   ca.dst[1] = wo_bf;   ca.n4[1] = 262144;
  ca.src[2] = Wk;   ca.dst[2] = wk_bf;   ca.n4[2] = 196608;
  ca.src[3] = Wkip; ca.dst[3] = wkip_bf; ca.n4[3] = 196608;
  ca.src[4] = Wv;   ca.dst[4] = wv_bf;   ca.n4[4] = 196608;
  ca.src[5] = Wvip; ca.dst[5] = wvip_bf; ca.n4[5] = 196608;
  k_cvt_all<<<dim3(1024, 6), 256, 0, stream>>>(ca);
  k_build_xn<<<dim3(96, 8), 256, 0, stream>>>(enc, lnw, lnb, xn);
  k_kv<<<dim3(4, 8), 256, 0, stream>>>(xn, wk_bf, wkip_bf, kall, 0);
  k_kv<<<dim3(4, 8), 256, 0, stream>>>(xn, wv_bf, wvip_bf, vtall, 1);
  k_qg8<<<512, 512, 0, stream>>>(hs, wq_bf, Qbuf);
  k_attn<<<dim3(32, 128), 256, 0, stream>>>(Qbuf, kall, vtall, attn);
  k_og8<<<512, 512, 0, stream>>>(attn, wo_bf, bo, out);
}

// Round 9
// 393.419 us; speedup vs baseline: 1.1130x; 1.0415x over previous
//
#include <hip/hip_runtime.h>
#include <hip/hip_bf16.h>
#include <stdint.h>

// ---------------------------------------------------------------------------
// CrossViewIPAttnProcessor on MI355X (gfx950)
// B=8, Lq=4096, D=1024, Dc=768, H=16, HD=64, text=77 keys, ip=4 keys
// Round 9: ATTENTION FUSED INTO Q-GEMM EPILOGUE. Each qg8 wave's 128x64
// output tile = one head x 128 q-rows (full head dim) -> per-wave attention
// with no cross-wave traffic: acc -> LDS (as before), Q-frags read back,
// QK^T + dual softmax + PV with K/V hoisted to registers, coalesced bf16
// attn-out via 4KB/wave P-scratch. k_attn kernel + 128MB Q round-trip gone.
// LDS = 128KB (AS/BS dbuf) + 32KB (P scratch) = 160KB.
// ---------------------------------------------------------------------------

typedef __attribute__((ext_vector_type(8))) short short8;
typedef __attribute__((ext_vector_type(4))) float f32x4;
typedef __attribute__((ext_vector_type(8))) float float8_t;
typedef __attribute__((ext_vector_type(8))) __bf16 bf16x8;
typedef __attribute__((ext_vector_type(4))) __bf16 bf16x4;

__device__ __forceinline__ ushort f2b(float f) {
  __bf16 h = (__bf16)f;
  return __builtin_bit_cast(ushort, h);
}

__device__ __forceinline__ short8 pack2(float4 a, float4 b) {
  float8_t v;
  v[0] = a.x; v[1] = a.y; v[2] = a.z; v[3] = a.w;
  v[4] = b.x; v[5] = b.y; v[6] = b.z; v[7] = b.w;
  return __builtin_bit_cast(short8, __builtin_convertvector(v, bf16x8));
}

#define GLD16(gp, lp) \
  __builtin_amdgcn_global_load_lds((const __attribute__((address_space(1))) uint32_t*)(gp), \
                                   (__attribute__((address_space(3))) uint32_t*)(lp), 16, 0, 0)

#define FENCE_SCHED() __builtin_amdgcn_sched_barrier(0)

// --------------------- 1) fused fp32 -> bf16 for 6 weights ------------------
struct CvtArgs {
  const float* src[6];
  ushort* dst[6];
  int n4[6];
};

__global__ __launch_bounds__(256) void k_cvt_all(CvtArgs a) {
  int seg = blockIdx.y;
  int i = blockIdx.x * blockDim.x + threadIdx.x;
  if (i >= a.n4[seg]) return;
  float4 v = reinterpret_cast<const float4*>(a.src[seg])[i];
  bf16x4 h;
  h[0] = (__bf16)v.x; h[1] = (__bf16)v.y; h[2] = (__bf16)v.z; h[3] = (__bf16)v.w;
  reinterpret_cast<ushort4*>(a.dst[seg])[i] = __builtin_bit_cast(ushort4, h);
}

// --------------------------- 2) Xn builder ---------------------------------
__global__ __launch_bounds__(256) void k_build_xn(const float* __restrict__ enc,
                                                  const float* __restrict__ lnw,
                                                  const float* __restrict__ lnb,
                                                  ushort* __restrict__ xn) {
  const int Dc = 768;
  int tok = blockIdx.x, b = blockIdx.y, t = threadIdx.x;
  ushort* out = xn + ((size_t)b * 96 + tok) * Dc;
  bool padrow = (tok >= 84) || (tok >= 77 && tok < 80);
  if (padrow) { out[t] = 0; out[t + 256] = 0; out[t + 512] = 0; return; }
  const float* src = (tok < 77) ? enc + ((size_t)b * 81 + tok) * Dc
                                : enc + ((size_t)b * 81 + 77 + (tok - 80)) * Dc;
  float x0 = src[t], x1 = src[t + 256], x2 = src[t + 512];
  if (tok >= 80) { out[t] = f2b(x0); out[t + 256] = f2b(x1); out[t + 512] = f2b(x2); return; }
  float s = x0 + x1 + x2, q = x0 * x0 + x1 * x1 + x2 * x2;
  for (int m = 32; m; m >>= 1) { s += __shfl_xor(s, m, 64); q += __shfl_xor(q, m, 64); }
  __shared__ float rs[4], rq[4];
  int w = t >> 6;
  if ((t & 63) == 0) { rs[w] = s; rq[w] = q; }
  __syncthreads();
  s = rs[0] + rs[1] + rs[2] + rs[3];
  q = rq[0] + rq[1] + rq[2] + rq[3];
  float mean = s * (1.0f / 768.0f);
  float var = q * (1.0f / 768.0f) - mean * mean;
  float rstd = rsqrtf(var + 1e-5f);
  out[t]       = f2b((x0 - mean) * rstd * lnw[t]       + lnb[t]);
  out[t + 256] = f2b((x1 - mean) * rstd * lnw[t + 256] + lnb[t + 256]);
  out[t + 512] = f2b((x2 - mean) * rstd * lnw[t + 512] + lnb[t + 512]);
}

// --------------------------- 3) K/V projection -----------------------------
__global__ __launch_bounds__(256) void k_kv(const ushort* __restrict__ xn,
                                            const ushort* __restrict__ wb,
                                            const ushort* __restrict__ wipb,
                                            ushort* __restrict__ out, int mode) {
  int n0 = blockIdx.x * 256, b = blockIdx.y;
  int t = threadIdx.x, w = t >> 6, l = t & 63, lo = l & 15, hi = l >> 4;
  __shared__ alignas(16) ushort Xs[96 * 32];
  __shared__ alignas(16) ushort Ws[256 * 32];
  __shared__ alignas(16) ushort Wip[256 * 32];
  f32x4 acc[6][4];
  f32x4 zf = {0.f, 0.f, 0.f, 0.f};
  for (int i = 0; i < 6; i++) for (int j = 0; j < 4; j++) acc[i][j] = zf;
  const ushort* xb = xn + (size_t)b * 96 * 768;
  for (int k0 = 0; k0 < 768; k0 += 32) {
    __syncthreads();
    for (int i = t; i < 96 * 16; i += 256) {
      int row = i >> 4, p = i & 15;
      reinterpret_cast<uint32_t*>(Xs)[i] =
          *reinterpret_cast<const uint32_t*>(xb + row * 768 + k0 + p * 2);
    }
    for (int i = t; i < 256 * 16; i += 256) {
      int row = i >> 4, p = i & 15;
      reinterpret_cast<uint32_t*>(Ws)[i] =
          *reinterpret_cast<const uint32_t*>(wb + (size_t)(n0 + row) * 768 + k0 + p * 2);
      reinterpret_cast<uint32_t*>(Wip)[i] =
          *reinterpret_cast<const uint32_t*>(wipb + (size_t)(n0 + row) * 768 + k0 + p * 2);
    }
    __syncthreads();
    short8 a[6], bb[4], bip[4];
    for (int mi = 0; mi < 6; mi++)
      a[mi] = *reinterpret_cast<const short8*>(Xs + (mi * 16 + lo) * 32 + hi * 8);
    for (int ni = 0; ni < 4; ni++) {
      bb[ni]  = *reinterpret_cast<const short8*>(Ws  + (w * 64 + ni * 16 + lo) * 32 + hi * 8);
      bip[ni] = *reinterpret_cast<const short8*>(Wip + (w * 64 + ni * 16 + lo) * 32 + hi * 8);
    }
    for (int ni = 0; ni < 4; ni++) {
      for (int mi = 0; mi < 5; mi++)
        acc[mi][ni] = __builtin_amdgcn_mfma_f32_16x16x32_bf16(a[mi], bb[ni], acc[mi][ni], 0, 0, 0);
      acc[5][ni] = __builtin_amdgcn_mfma_f32_16x16x32_bf16(a[5], bip[ni], acc[5][ni], 0, 0, 0);
    }
  }
  for (int mi = 0; mi < 6; mi++)
    for (int ni = 0; ni < 4; ni++) {
      int col = n0 + w * 64 + ni * 16 + lo;
      int h = col >> 6, dd = col & 63;
      for (int j = 0; j < 4; j++) {
        int tok = mi * 16 + hi * 4 + j;
        ushort v = f2b(acc[mi][ni][j]);
        if (mode == 0) out[(((size_t)b * 16 + h) * 96 + tok) * 64 + dd] = v;
        else           out[(((size_t)b * 16 + h) * 64 + dd) * 96 + tok] = v;
      }
    }
}

// ---------- 4+5) Q GEMM (8-phase, fp32 A reg-staged) + fused attention -----
__global__ __launch_bounds__(512, 2) void k_qg8(const float* __restrict__ A,
                                                const ushort* __restrict__ Bw,
                                                const ushort* __restrict__ Kall,
                                                const ushort* __restrict__ Vt,
                                                ushort* __restrict__ attnO) {
  const int K = 1024, NT = 16;
  int wg = blockIdx.x;
  int nid = (wg & 7) * 64 + (wg >> 3);      // XCD-chunked, nwg=512 (%8==0)
  int m0 = (nid >> 2) * 256, n0 = (nid & 3) * 256;
  int t = threadIdx.x, wid = t >> 6, l = t & 63, lo = l & 15, hi = l >> 4;
  int wr = wid >> 2, wc = wid & 3;
  __shared__ alignas(16) ushort SMEM[81920];        // 160KB
  ushort* ASb = SMEM;                                // A dbuf: 2 x 32KB
  ushort* BSb = SMEM + 32768;                        // B dbuf: 2 x 32KB
  f32x4 acc[8][4];
  f32x4 zf = {0.f, 0.f, 0.f, 0.f};
#pragma unroll
  for (int i = 0; i < 8; i++)
#pragma unroll
    for (int j = 0; j < 4; j++) acc[i][j] = zf;
  int tr = t >> 3, tc = t & 7;
  int tcs = tc ^ (tr & 7);                  // T2 pre-swizzled source chunk
  const float*  gA = A  + (size_t)(m0 + tr) * K + tcs * 8;
  const ushort* gB = Bw + (size_t)(n0 + tr) * K + tcs * 8;
  float4 av[4][2];

#define LD_A(kt_) do { \
    _Pragma("unroll") \
    for (int s = 0; s < 4; s++) { \
      av[s][0] = *reinterpret_cast<const float4*>(gA + (size_t)s * 64 * K + (kt_) * 64); \
      av[s][1] = *reinterpret_cast<const float4*>(gA + (size_t)s * 64 * K + (kt_) * 64 + 4); \
    } } while (0)
#define WR_A(s_, b_) \
    *reinterpret_cast<short8*>(&ASb[(b_) * 16384 + (s_) * 4096 + t * 8]) = pack2(av[s_][0], av[s_][1])
#define STG_B(kt_, s_, b_) GLD16(gB + (size_t)(s_) * 64 * K + (kt_) * 64, &BSb[(b_) * 16384 + (s_) * 4096 + wid * 512])

  // ---- prologue ----
  LD_A(0);
  STG_B(0, 0, 0); STG_B(0, 1, 0); STG_B(0, 2, 0); STG_B(0, 3, 0);
  STG_B(1, 0, 1); STG_B(1, 1, 1); STG_B(1, 2, 1); STG_B(1, 3, 1);
  WR_A(0, 0); WR_A(1, 0); WR_A(2, 0); WR_A(3, 0);
  LD_A(1);
  WR_A(0, 1); WR_A(1, 1); WR_A(2, 1); WR_A(3, 1);
  asm volatile("s_waitcnt lgkmcnt(0)" ::: "memory");
  __builtin_amdgcn_s_barrier();
  FENCE_SCHED();

  const int swz = (lo & 7) << 3;
  short8 af[4][2], af2[4][2], b01[2][2], b23[2][2];

  for (int kt = 0; kt < NT; kt++) {
    int cur = kt & 1, nxt = cur ^ 1;
    const ushort* sA = &ASb[cur * 16384];
    const ushort* sB = &BSb[cur * 16384];
    // phase 0: LD_A(t+1); af+b01 reads; MFMA q03xn01
    if (kt + 1 < NT) LD_A(kt + 1);
#pragma unroll
    for (int q = 0; q < 4; q++)
#pragma unroll
      for (int kk = 0; kk < 2; kk++)
        af[q][kk] = *reinterpret_cast<const short8*>(
            sA + (wr * 128 + q * 16 + lo) * 64 + ((hi * 8 + kk * 32) ^ swz));
#pragma unroll
    for (int n = 0; n < 2; n++)
#pragma unroll
      for (int kk = 0; kk < 2; kk++)
        b01[n][kk] = *reinterpret_cast<const short8*>(
            sB + (wc * 64 + n * 16 + lo) * 64 + ((hi * 8 + kk * 32) ^ swz));
    __builtin_amdgcn_s_barrier();
    FENCE_SCHED();
    __builtin_amdgcn_s_setprio(1);
#pragma unroll
    for (int q = 0; q < 4; q++)
#pragma unroll
      for (int n = 0; n < 2; n++)
#pragma unroll
        for (int kk = 0; kk < 2; kk++)
          acc[q][n] = __builtin_amdgcn_mfma_f32_16x16x32_bf16(af[q][kk], b01[n][kk], acc[q][n], 0, 0, 0);
    __builtin_amdgcn_s_setprio(0);
    __builtin_amdgcn_s_barrier();
    FENCE_SCHED();
    // phase 1: b23 reads; MFMA q03xn23
#pragma unroll
    for (int n = 0; n < 2; n++)
#pragma unroll
      for (int kk = 0; kk < 2; kk++)
        b23[n][kk] = *reinterpret_cast<const short8*>(
            sB + (wc * 64 + (2 + n) * 16 + lo) * 64 + ((hi * 8 + kk * 32) ^ swz));
    __builtin_amdgcn_s_barrier();
    FENCE_SCHED();
    __builtin_amdgcn_s_setprio(1);
#pragma unroll
    for (int q = 0; q < 4; q++)
#pragma unroll
      for (int n = 0; n < 2; n++)
#pragma unroll
        for (int kk = 0; kk < 2; kk++)
          acc[q][2 + n] = __builtin_amdgcn_mfma_f32_16x16x32_bf16(af[q][kk], b23[n][kk], acc[q][2 + n], 0, 0, 0);
    __builtin_amdgcn_s_setprio(0);
    __builtin_amdgcn_s_barrier();
    FENCE_SCHED();
    // phase 2: af2 reads; B(t+2)s01; A(t+1)s01 writes; MFMA q47xn23
#pragma unroll
    for (int q = 0; q < 4; q++)
#pragma unroll
      for (int kk = 0; kk < 2; kk++)
        af2[q][kk] = *reinterpret_cast<const short8*>(
            sA + (wr * 128 + (4 + q) * 16 + lo) * 64 + ((hi * 8 + kk * 32) ^ swz));
    if (kt + 2 < NT) { STG_B(kt + 2, 0, cur); STG_B(kt + 2, 1, cur); }
    if (kt + 1 < NT) { WR_A(0, nxt); WR_A(1, nxt); }
    asm volatile("s_waitcnt lgkmcnt(0)" ::: "memory");
    __builtin_amdgcn_s_barrier();
    FENCE_SCHED();
    __builtin_amdgcn_s_setprio(1);
#pragma unroll
    for (int q = 0; q < 4; q++)
#pragma unroll
      for (int n = 0; n < 2; n++)
#pragma unroll
        for (int kk = 0; kk < 2; kk++)
          acc[4 + q][2 + n] = __builtin_amdgcn_mfma_f32_16x16x32_bf16(af2[q][kk], b23[n][kk], acc[4 + q][2 + n], 0, 0, 0);
    __builtin_amdgcn_s_setprio(0);
    __builtin_amdgcn_s_barrier();
    FENCE_SCHED();
    // phase 3: B(t+2)s23; A(t+1)s23 writes; vmcnt(4); MFMA q47xn01
    if (kt + 2 < NT) { STG_B(kt + 2, 2, cur); STG_B(kt + 2, 3, cur); }
    if (kt + 1 < NT) { WR_A(2, nxt); WR_A(3, nxt); }
    asm volatile("s_waitcnt vmcnt(4)" ::: "memory");
    asm volatile("s_waitcnt lgkmcnt(0)" ::: "memory");
    __builtin_amdgcn_s_barrier();
    FENCE_SCHED();
    __builtin_amdgcn_s_setprio(1);
#pragma unroll
    for (int q = 0; q < 4; q++)
#pragma unroll
      for (int n = 0; n < 2; n++)
#pragma unroll
        for (int kk = 0; kk < 2; kk++)
          acc[4 + q][n] = __builtin_amdgcn_mfma_f32_16x16x32_bf16(af2[q][kk], b01[n][kk], acc[4 + q][n], 0, 0, 0);
    __builtin_amdgcn_s_setprio(0);
    __builtin_amdgcn_s_barrier();
    FENCE_SCHED();
  }
#undef LD_A
#undef WR_A
#undef STG_B

  // =================== fused attention epilogue (per wave) ==================
  __syncthreads();                       // all waves done with AS/BS
  // (a) stage Q tile: wave-local [128][64], chunk ^ (row&7) swizzle
  ushort* ep = SMEM + wid * 8192;
#pragma unroll
  for (int mi = 0; mi < 8; mi++)
#pragma unroll
    for (int n = 0; n < 4; n++)
#pragma unroll
      for (int j = 0; j < 4; j++) {
        int row_l = mi * 16 + hi * 4 + j;
        int col = n * 16 + lo;
        ep[row_l * 64 + (((col >> 3) ^ (row_l & 7)) << 3) + (col & 7)] = f2b(acc[mi][n][j]);
      }
  // (b) per-wave head attention
  ushort* PS = SMEM + 65536 + wid * 2048;     // 4KB P / out scratch
  int b = m0 >> 12;
  int h = (n0 >> 6) + wc;
  const ushort* Kb = Kall + (size_t)(b * 16 + h) * 96 * 64;
  const ushort* Vb = Vt + (size_t)(b * 16 + h) * 64 * 96;
  short8 kf[6][2], vf[3][4];
#pragma unroll
  for (int ni = 0; ni < 6; ni++)
#pragma unroll
    for (int ks = 0; ks < 2; ks++)
      kf[ni][ks] = *reinterpret_cast<const short8*>(Kb + (ni * 16 + lo) * 64 + ks * 32 + hi * 8);
#pragma unroll
  for (int kk = 0; kk < 3; kk++)
#pragma unroll
    for (int dn = 0; dn < 4; dn++)
      vf[kk][dn] = *reinterpret_cast<const short8*>(Vb + (dn * 16 + lo) * 96 + kk * 32 + hi * 8);
  const float SC = 0.125f * 1.44269504088896340736f;  // 1/sqrt(64) * log2(e)
  for (int mi = 0; mi < 8; mi++) {
    // Q frags from LDS (row = mi*16+lo, k = ks*32+hi*8, chunk-swizzled)
    short8 qf[2];
#pragma unroll
    for (int ks = 0; ks < 2; ks++)
      qf[ks] = *reinterpret_cast<const short8*>(
          &ep[(mi * 16 + lo) * 64 + (((ks * 4 + hi) ^ (lo & 7)) << 3)]);
    f32x4 s[6];
#pragma unroll
    for (int ni = 0; ni < 6; ni++) {
      s[ni] = zf;
#pragma unroll
      for (int ks = 0; ks < 2; ks++)
        s[ni] = __builtin_amdgcn_mfma_f32_16x16x32_bf16(qf[ks], kf[ni][ks], s[ni], 0, 0, 0);
    }
    // dual softmax per output row (row = hi*4+j), keys spread over 16 lo lanes
#pragma unroll
    for (int j = 0; j < 4; j++) {
      float pb[5];
      float mb = -1e30f;
#pragma unroll
      for (int ni = 0; ni < 5; ni++) {
        int c = ni * 16 + lo;
        float v = s[ni][j] * SC;
        pb[ni] = v;
        if (c < 77) mb = fmaxf(mb, v);
      }
      mb = fmaxf(mb, __shfl_xor(mb, 1, 64));
      mb = fmaxf(mb, __shfl_xor(mb, 2, 64));
      mb = fmaxf(mb, __shfl_xor(mb, 4, 64));
      mb = fmaxf(mb, __shfl_xor(mb, 8, 64));
      float sb = 0.f;
#pragma unroll
      for (int ni = 0; ni < 5; ni++) {
        int c = ni * 16 + lo;
        float p = (c < 77) ? exp2f(pb[ni] - mb) : 0.f;
        pb[ni] = p; sb += p;
      }
      sb += __shfl_xor(sb, 1, 64); sb += __shfl_xor(sb, 2, 64);
      sb += __shfl_xor(sb, 4, 64); sb += __shfl_xor(sb, 8, 64);
      float rb = 1.0f / sb;
      // ip softmax over lanes lo<4 (cols 80..83); guard masked-lane write
      float vip = s[5][j] * SC;
      bool val = lo < 4;
      float mip = val ? vip : -1e30f;
      mip = fmaxf(mip, __shfl_xor(mip, 1, 64));
      mip = fmaxf(mip, __shfl_xor(mip, 2, 64));
      float pi = val ? exp2f(vip - mip) : 0.f;
      float si = pi;
      si += __shfl_xor(si, 1, 64); si += __shfl_xor(si, 2, 64);
      float ri = 1.0f / si;
      ushort* pr = &PS[(hi * 4 + j) * 104];
#pragma unroll
      for (int ni = 0; ni < 5; ni++) pr[ni * 16 + lo] = f2b(pb[ni] * rb);
      pr[80 + lo] = f2b(val ? pi * ri : 0.f);
    }
    // PV
    f32x4 o[4];
#pragma unroll
    for (int dn = 0; dn < 4; dn++) o[dn] = zf;
#pragma unroll
    for (int kk = 0; kk < 3; kk++) {
      short8 pf = *reinterpret_cast<const short8*>(&PS[lo * 104 + kk * 32 + hi * 8]);
#pragma unroll
      for (int dn = 0; dn < 4; dn++)
        o[dn] = __builtin_amdgcn_mfma_f32_16x16x32_bf16(pf, vf[kk][dn], o[dn], 0, 0, 0);
    }
    // stage o -> PS (P consumed), then coalesced 16B stores
#pragma unroll
    for (int dn = 0; dn < 4; dn++)
#pragma unroll
      for (int j = 0; j < 4; j++)
        PS[(hi * 4 + j) * 64 + dn * 16 + lo] = f2b(o[dn][j]);
    int gr0 = m0 + wr * 128 + mi * 16;
#pragma unroll
    for (int it = 0; it < 2; it++) {
      int row_o = it * 8 + (l >> 3), c8 = l & 7;
      short8 v = *reinterpret_cast<const short8*>(&PS[row_o * 64 + c8 * 8]);
      *reinterpret_cast<short8*>(&attnO[(size_t)(gr0 + row_o) * 1024 + h * 64 + c8 * 8]) = v;
    }
  }
}

// ------------------- 6) out GEMM: 8-phase, bf16 A, fp32 C + bias -----------
__global__ __launch_bounds__(512, 2) void k_og8(const ushort* __restrict__ A,
                                                const ushort* __restrict__ Bw,
                                                const float* __restrict__ bias,
                                                float* __restrict__ C) {
  const int K = 1024, NT = 16;
  int wg = blockIdx.x;
  int nid = (wg & 7) * 64 + (wg >> 3);
  int m0 = (nid >> 2) * 256, n0 = (nid & 3) * 256;
  int t = threadIdx.x, wid = t >> 6, l = t & 63, lo = l & 15, hi = l >> 4;
  int wr = wid >> 2, wc = wid & 3;
  __shared__ alignas(16) ushort AS[2][256 * 64];
  __shared__ alignas(16) ushort BS[2][256 * 64];
  f32x4 acc[8][4];
  f32x4 zf = {0.f, 0.f, 0.f, 0.f};
#pragma unroll
  for (int i = 0; i < 8; i++)
#pragma unroll
    for (int j = 0; j < 4; j++) acc[i][j] = zf;
  int tr = t >> 3, tc = t & 7;
  int tcs = tc ^ (tr & 7);
  const ushort* gA = A  + (size_t)(m0 + tr) * K + tcs * 8;
  const ushort* gB = Bw + (size_t)(n0 + tr) * K + tcs * 8;

#define STG_A(kt_, s_, b_) GLD16(gA + (size_t)(s_) * 64 * K + (kt_) * 64, &AS[b_][(s_) * 4096 + wid * 512])
#define STG_B(kt_, s_, b_) GLD16(gB + (size_t)(s_) * 64 * K + (kt_) * 64, &BS[b_][(s_) * 4096 + wid * 512])

  STG_A(0, 0, 0); STG_A(0, 1, 0); STG_A(0, 2, 0); STG_A(0, 3, 0);
  STG_B(0, 0, 0); STG_B(0, 1, 0); STG_B(0, 2, 0); STG_B(0, 3, 0);
  STG_B(1, 0, 1); STG_B(1, 1, 1); STG_B(1, 2, 1); STG_B(1, 3, 1);
  STG_A(1, 0, 1); STG_A(1, 1, 1);
  asm volatile("s_waitcnt vmcnt(6)" ::: "memory");
  __builtin_amdgcn_s_barrier();
  FENCE_SCHED();

  const int swz = (lo & 7) << 3;
  short8 af[4][2], af2[4][2], b01[2][2], b23[2][2];

  for (int kt = 0; kt < NT; kt++) {
    int cur = kt & 1, nxt = cur ^ 1;
    const ushort* sA = &AS[cur][0];
    const ushort* sB = &BS[cur][0];
    // phase 0
#pragma unroll
    for (int q = 0; q < 4; q++)
#pragma unroll
      for (int kk = 0; kk < 2; kk++)
        af[q][kk] = *reinterpret_cast<const short8*>(
            sA + (wr * 128 + q * 16 + lo) * 64 + ((hi * 8 + kk * 32) ^ swz));
#pragma unroll
    for (int n = 0; n < 2; n++)
#pragma unroll
      for (int kk = 0; kk < 2; kk++)
        b01[n][kk] = *reinterpret_cast<const short8*>(
            sB + (wc * 64 + n * 16 + lo) * 64 + ((hi * 8 + kk * 32) ^ swz));
    if (kt + 1 < NT) { STG_A(kt + 1, 2, nxt); STG_A(kt + 1, 3, nxt); }
    __builtin_amdgcn_s_barrier();
    FENCE_SCHED();
    __builtin_amdgcn_s_setprio(1);
#pragma unroll
    for (int q = 0; q < 4; q++)
#pragma unroll
      for (int n = 0; n < 2; n++)
#pragma unroll
        for (int kk = 0; kk < 2; kk++)
          acc[q][n] = __builtin_amdgcn_mfma_f32_16x16x32_bf16(af[q][kk], b01[n][kk], acc[q][n], 0, 0, 0);
    __builtin_amdgcn_s_setprio(0);
    __builtin_amdgcn_s_barrier();
    FENCE_SCHED();
    // phase 1
#pragma unroll
    for (int n = 0; n < 2; n++)
#pragma unroll
      for (int kk = 0; kk < 2; kk++)
        b23[n][kk] = *reinterpret_cast<const short8*>(
            sB + (wc * 64 + (2 + n) * 16 + lo) * 64 + ((hi * 8 + kk * 32) ^ swz));
    __builtin_amdgcn_s_barrier();
    FENCE_SCHED();
    __builtin_amdgcn_s_setprio(1);
#pragma unroll
    for (int q = 0; q < 4; q++)
#pragma unroll
      for (int n = 0; n < 2; n++)
#pragma unroll
        for (int kk = 0; kk < 2; kk++)
          acc[q][2 + n] = __builtin_amdgcn_mfma_f32_16x16x32_bf16(af[q][kk], b23[n][kk], acc[q][2 + n], 0, 0, 0);
    __builtin_amdgcn_s_setprio(0);
    __builtin_amdgcn_s_barrier();
    FENCE_SCHED();
    // phase 2
#pragma unroll
    for (int q = 0; q < 4; q++)
#pragma unroll
      for (int kk = 0; kk < 2; kk++)
        af2[q][kk] = *reinterpret_cast<const short8*>(
            sA + (wr * 128 + (4 + q) * 16 + lo) * 64 + ((hi * 8 + kk * 32) ^ swz));
    if (kt + 2 < NT) { STG_B(kt + 2, 0, cur); STG_B(kt + 2, 1, cur); }
    __builtin_amdgcn_s_barrier();
    FENCE_SCHED();
    __builtin_amdgcn_s_setprio(1);
#pragma unroll
    for (int q = 0; q < 4; q++)
#pragma unroll
      for (int n = 0; n < 2; n++)
#pragma unroll
        for (int kk = 0; kk < 2; kk++)
          acc[4 + q][2 + n] = __builtin_amdgcn_mfma_f32_16x16x32_bf16(af2[q][kk], b23[n][kk], acc[4 + q][2 + n], 0, 0, 0);
    __builtin_amdgcn_s_setprio(0);
    __builtin_amdgcn_s_barrier();
    FENCE_SCHED();
    // phase 3
    if (kt + 2 < NT) {
      STG_B(kt + 2, 2, cur); STG_B(kt + 2, 3, cur);
      STG_A(kt + 2, 0, cur); STG_A(kt + 2, 1, cur);
      asm volatile("s_waitcnt vmcnt(6)" ::: "memory");
    } else {
      asm volatile("s_waitcnt vmcnt(0)" ::: "memory");
    }
    __builtin_amdgcn_s_barrier();
    FENCE_SCHED();
    __builtin_amdgcn_s_setprio(1);
#pragma unroll
    for (int q = 0; q < 4; q++)
#pragma unroll
      for (int n = 0; n < 2; n++)
#pragma unroll
        for (int kk = 0; kk < 2; kk++)
          acc[4 + q][n] = __builtin_amdgcn_mfma_f32_16x16x32_bf16(af2[q][kk], b01[n][kk], acc[4 + q][n], 0, 0, 0);
    __builtin_amdgcn_s_setprio(0);
    __builtin_amdgcn_s_barrier();
    FENCE_SCHED();
  }
#pragma unroll
  for (int n = 0; n < 4; n++) {
    int c = n0 + wc * 64 + n * 16 + lo;
    float bv = bias[c];
#pragma unroll
    for (int mi = 0; mi < 8; mi++)
#pragma unroll
      for (int j = 0; j < 4; j++) {
        int r = m0 + wr * 128 + mi * 16 + hi * 4 + j;
        C[(size_t)r * 1024 + c] = acc[mi][n][j] + bv;
      }
  }
#undef STG_A
#undef STG_B
}

// ---------------------------------------------------------------------------
extern "C" void kernel_launch(void* const* d_in, const int* in_sizes, int n_in,
                              void* d_out, int out_size, void* d_ws, size_t ws_size,
                              hipStream_t stream) {
  const float* hs   = (const float*)d_in[0];
  const float* enc  = (const float*)d_in[1];
  const float* Wq   = (const float*)d_in[2];
  const float* Wk   = (const float*)d_in[3];
  const float* Wv   = (const float*)d_in[4];
  const float* Wkip = (const float*)d_in[5];
  const float* Wvip = (const float*)d_in[6];
  const float* Wo   = (const float*)d_in[7];
  const float* bo   = (const float*)d_in[8];
  const float* lnw  = (const float*)d_in[9];
  const float* lnb  = (const float*)d_in[10];
  float* out = (float*)d_out;

  ushort* p = (ushort*)d_ws;
  ushort* attn    = p; p += (size_t)32768 * 1024;
  ushort* wq_bf   = p; p += (size_t)1024 * 1024;
  ushort* wo_bf   = p; p += (size_t)1024 * 1024;
  ushort* wk_bf   = p; p += (size_t)1024 * 768;
  ushort* wkip_bf = p; p += (size_t)1024 * 768;
  ushort* wv_bf   = p; p += (size_t)1024 * 768;
  ushort* wvip_bf = p; p += (size_t)1024 * 768;
  ushort* xn      = p; p += (size_t)8 * 96 * 768;
  ushort* kall    = p; p += (size_t)8 * 16 * 96 * 64;
  ushort* vtall   = p; p += (size_t)8 * 16 * 96 * 64;

  CvtArgs ca;
  ca.src[0] = Wq;   ca.dst[0] = wq_bf;   ca.n4[0] = 262144;
  ca.src[1] = Wo;   ca.dst[1] = wo_bf;   ca.n4[1] = 262144;
  ca.src[2] = Wk;   ca.dst[2] = wk_bf;   ca.n4[2] = 196608;
  ca.src[3] = Wkip; ca.dst[3] = wkip_bf; ca.n4[3] = 196608;
  ca.src[4] = Wv;   ca.dst[4] = wv_bf;   ca.n4[4] = 196608;
  ca.src[5] = Wvip; ca.dst[5] = wvip_bf; ca.n4[5] = 196608;
  k_cvt_all<<<dim3(1024, 6), 256, 0, stream>>>(ca);
  k_build_xn<<<dim3(96, 8), 256, 0, stream>>>(enc, lnw, lnb, xn);
  k_kv<<<dim3(4, 8), 256, 0, stream>>>(xn, wk_bf, wkip_bf, kall, 0);
  k_kv<<<dim3(4, 8), 256, 0, stream>>>(xn, wv_bf, wvip_bf, vtall, 1);
  k_qg8<<<512, 512, 0, stream>>>(hs, wq_bf, kall, vtall, attn);
  k_og8<<<512, 512, 0, stream>>>(attn, wo_bf, bo, out);
}

// Round 10
// 328.047 us; speedup vs baseline: 1.3348x; 1.1993x over previous
//
#include <hip/hip_runtime.h>
#include <hip/hip_bf16.h>
#include <stdint.h>

// ---------------------------------------------------------------------------
// CrossViewIPAttnProcessor on MI355X (gfx950)
// B=8, Lq=4096, D=1024, Dc=768, H=16, HD=64, text=77 keys, ip=4 keys
// Round 10:
//  - qg8 attn epilogue: QK(mi+1) moved between P-write(mi) and PV-read(mi)
//    (MFMA covers DS latency); P stores UNNORMALIZED exp (ip pre-scaled by
//    sb/si); o scaled by rb post-PV. Saves the serial DS stall + VALU.
//  - k_kv x2 -> one dispatch (blockIdx.z = K/V), 64 concurrent blocks.
//  - k_cvt_all + k_build_xn -> one k_prep dispatch.
// ---------------------------------------------------------------------------

typedef __attribute__((ext_vector_type(8))) short short8;
typedef __attribute__((ext_vector_type(4))) float f32x4;
typedef __attribute__((ext_vector_type(8))) float float8_t;
typedef __attribute__((ext_vector_type(8))) __bf16 bf16x8;
typedef __attribute__((ext_vector_type(4))) __bf16 bf16x4;

__device__ __forceinline__ ushort f2b(float f) {
  __bf16 h = (__bf16)f;
  return __builtin_bit_cast(ushort, h);
}

__device__ __forceinline__ short8 pack2(float4 a, float4 b) {
  float8_t v;
  v[0] = a.x; v[1] = a.y; v[2] = a.z; v[3] = a.w;
  v[4] = b.x; v[5] = b.y; v[6] = b.z; v[7] = b.w;
  return __builtin_bit_cast(short8, __builtin_convertvector(v, bf16x8));
}

#define GLD16(gp, lp) \
  __builtin_amdgcn_global_load_lds((const __attribute__((address_space(1))) uint32_t*)(gp), \
                                   (__attribute__((address_space(3))) uint32_t*)(lp), 16, 0, 0)

#define FENCE_SCHED() __builtin_amdgcn_sched_barrier(0)

// -------- 1+2) fused prep: 6 weight fp32->bf16 segs + Xn builder -----------
struct CvtArgs {
  const float* src[6];
  ushort* dst[6];
  int n4[6];
};

__global__ __launch_bounds__(256) void k_prep(CvtArgs a,
                                              const float* __restrict__ enc,
                                              const float* __restrict__ lnw,
                                              const float* __restrict__ lnb,
                                              ushort* __restrict__ xn) {
  int seg = blockIdx.y;
  if (seg < 6) {
    int i = blockIdx.x * blockDim.x + threadIdx.x;
    if (i >= a.n4[seg]) return;
    float4 v = reinterpret_cast<const float4*>(a.src[seg])[i];
    bf16x4 h;
    h[0] = (__bf16)v.x; h[1] = (__bf16)v.y; h[2] = (__bf16)v.z; h[3] = (__bf16)v.w;
    reinterpret_cast<ushort4*>(a.dst[seg])[i] = __builtin_bit_cast(ushort4, h);
    return;
  }
  // seg == 6: Xn builder (768 blocks used)
  if (blockIdx.x >= 768) return;
  const int Dc = 768;
  int tok = blockIdx.x % 96, b = blockIdx.x / 96, t = threadIdx.x;
  ushort* out = xn + ((size_t)b * 96 + tok) * Dc;
  bool padrow = (tok >= 84) || (tok >= 77 && tok < 80);
  if (padrow) { out[t] = 0; out[t + 256] = 0; out[t + 512] = 0; return; }
  const float* src = (tok < 77) ? enc + ((size_t)b * 81 + tok) * Dc
                                : enc + ((size_t)b * 81 + 77 + (tok - 80)) * Dc;
  float x0 = src[t], x1 = src[t + 256], x2 = src[t + 512];
  if (tok >= 80) { out[t] = f2b(x0); out[t + 256] = f2b(x1); out[t + 512] = f2b(x2); return; }
  float s = x0 + x1 + x2, q = x0 * x0 + x1 * x1 + x2 * x2;
  for (int m = 32; m; m >>= 1) { s += __shfl_xor(s, m, 64); q += __shfl_xor(q, m, 64); }
  __shared__ float rs[4], rq[4];
  int w = t >> 6;
  if ((t & 63) == 0) { rs[w] = s; rq[w] = q; }
  __syncthreads();
  s = rs[0] + rs[1] + rs[2] + rs[3];
  q = rq[0] + rq[1] + rq[2] + rq[3];
  float mean = s * (1.0f / 768.0f);
  float var = q * (1.0f / 768.0f) - mean * mean;
  float rstd = rsqrtf(var + 1e-5f);
  out[t]       = f2b((x0 - mean) * rstd * lnw[t]       + lnb[t]);
  out[t + 256] = f2b((x1 - mean) * rstd * lnw[t + 256] + lnb[t + 256]);
  out[t + 512] = f2b((x2 - mean) * rstd * lnw[t + 512] + lnb[t + 512]);
}

// ------------------ 3) K/V projection (merged, blockIdx.z = mode) ----------
__global__ __launch_bounds__(256) void k_kv(const ushort* __restrict__ xn,
                                            const ushort* __restrict__ wk,
                                            const ushort* __restrict__ wkip,
                                            const ushort* __restrict__ wv,
                                            const ushort* __restrict__ wvip,
                                            ushort* __restrict__ kall,
                                            ushort* __restrict__ vtall) {
  int mode = blockIdx.z;
  const ushort* wb   = mode ? wv   : wk;
  const ushort* wipb = mode ? wvip : wkip;
  ushort* out        = mode ? vtall : kall;
  int n0 = blockIdx.x * 256, b = blockIdx.y;
  int t = threadIdx.x, w = t >> 6, l = t & 63, lo = l & 15, hi = l >> 4;
  __shared__ alignas(16) ushort Xs[96 * 32];
  __shared__ alignas(16) ushort Ws[256 * 32];
  __shared__ alignas(16) ushort Wip[256 * 32];
  f32x4 acc[6][4];
  f32x4 zf = {0.f, 0.f, 0.f, 0.f};
  for (int i = 0; i < 6; i++) for (int j = 0; j < 4; j++) acc[i][j] = zf;
  const ushort* xb = xn + (size_t)b * 96 * 768;
  for (int k0 = 0; k0 < 768; k0 += 32) {
    __syncthreads();
    for (int i = t; i < 96 * 16; i += 256) {
      int row = i >> 4, p = i & 15;
      reinterpret_cast<uint32_t*>(Xs)[i] =
          *reinterpret_cast<const uint32_t*>(xb + row * 768 + k0 + p * 2);
    }
    for (int i = t; i < 256 * 16; i += 256) {
      int row = i >> 4, p = i & 15;
      reinterpret_cast<uint32_t*>(Ws)[i] =
          *reinterpret_cast<const uint32_t*>(wb + (size_t)(n0 + row) * 768 + k0 + p * 2);
      reinterpret_cast<uint32_t*>(Wip)[i] =
          *reinterpret_cast<const uint32_t*>(wipb + (size_t)(n0 + row) * 768 + k0 + p * 2);
    }
    __syncthreads();
    short8 a[6], bb[4], bip[4];
    for (int mi = 0; mi < 6; mi++)
      a[mi] = *reinterpret_cast<const short8*>(Xs + (mi * 16 + lo) * 32 + hi * 8);
    for (int ni = 0; ni < 4; ni++) {
      bb[ni]  = *reinterpret_cast<const short8*>(Ws  + (w * 64 + ni * 16 + lo) * 32 + hi * 8);
      bip[ni] = *reinterpret_cast<const short8*>(Wip + (w * 64 + ni * 16 + lo) * 32 + hi * 8);
    }
    for (int ni = 0; ni < 4; ni++) {
      for (int mi = 0; mi < 5; mi++)
        acc[mi][ni] = __builtin_amdgcn_mfma_f32_16x16x32_bf16(a[mi], bb[ni], acc[mi][ni], 0, 0, 0);
      acc[5][ni] = __builtin_amdgcn_mfma_f32_16x16x32_bf16(a[5], bip[ni], acc[5][ni], 0, 0, 0);
    }
  }
  for (int mi = 0; mi < 6; mi++)
    for (int ni = 0; ni < 4; ni++) {
      int col = n0 + w * 64 + ni * 16 + lo;
      int h = col >> 6, dd = col & 63;
      for (int j = 0; j < 4; j++) {
        int tok = mi * 16 + hi * 4 + j;
        ushort v = f2b(acc[mi][ni][j]);
        if (mode == 0) out[(((size_t)b * 16 + h) * 96 + tok) * 64 + dd] = v;
        else           out[(((size_t)b * 16 + h) * 64 + dd) * 96 + tok] = v;
      }
    }
}

// ---------- 4+5) Q GEMM (8-phase, fp32 A reg-staged) + fused attention -----
__global__ __launch_bounds__(512, 2) void k_qg8(const float* __restrict__ A,
                                                const ushort* __restrict__ Bw,
                                                const ushort* __restrict__ Kall,
                                                const ushort* __restrict__ Vt,
                                                ushort* __restrict__ attnO) {
  const int K = 1024, NT = 16;
  int wg = blockIdx.x;
  int nid = (wg & 7) * 64 + (wg >> 3);      // XCD-chunked, nwg=512 (%8==0)
  int m0 = (nid >> 2) * 256, n0 = (nid & 3) * 256;
  int t = threadIdx.x, wid = t >> 6, l = t & 63, lo = l & 15, hi = l >> 4;
  int wr = wid >> 2, wc = wid & 3;
  __shared__ alignas(16) ushort SMEM[81920];        // 160KB
  ushort* ASb = SMEM;                                // A dbuf: 2 x 32KB
  ushort* BSb = SMEM + 32768;                        // B dbuf: 2 x 32KB
  f32x4 acc[8][4];
  f32x4 zf = {0.f, 0.f, 0.f, 0.f};
#pragma unroll
  for (int i = 0; i < 8; i++)
#pragma unroll
    for (int j = 0; j < 4; j++) acc[i][j] = zf;
  int tr = t >> 3, tc = t & 7;
  int tcs = tc ^ (tr & 7);                  // T2 pre-swizzled source chunk
  const float*  gA = A  + (size_t)(m0 + tr) * K + tcs * 8;
  const ushort* gB = Bw + (size_t)(n0 + tr) * K + tcs * 8;
  float4 av[4][2];

#define LD_A(kt_) do { \
    _Pragma("unroll") \
    for (int s_ = 0; s_ < 4; s_++) { \
      av[s_][0] = *reinterpret_cast<const float4*>(gA + (size_t)s_ * 64 * K + (kt_) * 64); \
      av[s_][1] = *reinterpret_cast<const float4*>(gA + (size_t)s_ * 64 * K + (kt_) * 64 + 4); \
    } } while (0)
#define WR_A(s_, b_) \
    *reinterpret_cast<short8*>(&ASb[(b_) * 16384 + (s_) * 4096 + t * 8]) = pack2(av[s_][0], av[s_][1])
#define STG_B(kt_, s_, b_) GLD16(gB + (size_t)(s_) * 64 * K + (kt_) * 64, &BSb[(b_) * 16384 + (s_) * 4096 + wid * 512])

  // ---- prologue ----
  LD_A(0);
  STG_B(0, 0, 0); STG_B(0, 1, 0); STG_B(0, 2, 0); STG_B(0, 3, 0);
  STG_B(1, 0, 1); STG_B(1, 1, 1); STG_B(1, 2, 1); STG_B(1, 3, 1);
  WR_A(0, 0); WR_A(1, 0); WR_A(2, 0); WR_A(3, 0);
  LD_A(1);
  WR_A(0, 1); WR_A(1, 1); WR_A(2, 1); WR_A(3, 1);
  asm volatile("s_waitcnt lgkmcnt(0)" ::: "memory");
  __builtin_amdgcn_s_barrier();
  FENCE_SCHED();

  const int swz = (lo & 7) << 3;
  short8 af[4][2], af2[4][2], b01[2][2], b23[2][2];

  for (int kt = 0; kt < NT; kt++) {
    int cur = kt & 1, nxt = cur ^ 1;
    const ushort* sA = &ASb[cur * 16384];
    const ushort* sB = &BSb[cur * 16384];
    // phase 0: LD_A(t+1); af+b01 reads; MFMA q03xn01
    if (kt + 1 < NT) LD_A(kt + 1);
#pragma unroll
    for (int q = 0; q < 4; q++)
#pragma unroll
      for (int kk = 0; kk < 2; kk++)
        af[q][kk] = *reinterpret_cast<const short8*>(
            sA + (wr * 128 + q * 16 + lo) * 64 + ((hi * 8 + kk * 32) ^ swz));
#pragma unroll
    for (int n = 0; n < 2; n++)
#pragma unroll
      for (int kk = 0; kk < 2; kk++)
        b01[n][kk] = *reinterpret_cast<const short8*>(
            sB + (wc * 64 + n * 16 + lo) * 64 + ((hi * 8 + kk * 32) ^ swz));
    __builtin_amdgcn_s_barrier();
    FENCE_SCHED();
    __builtin_amdgcn_s_setprio(1);
#pragma unroll
    for (int q = 0; q < 4; q++)
#pragma unroll
      for (int n = 0; n < 2; n++)
#pragma unroll
        for (int kk = 0; kk < 2; kk++)
          acc[q][n] = __builtin_amdgcn_mfma_f32_16x16x32_bf16(af[q][kk], b01[n][kk], acc[q][n], 0, 0, 0);
    __builtin_amdgcn_s_setprio(0);
    __builtin_amdgcn_s_barrier();
    FENCE_SCHED();
    // phase 1: b23 reads; MFMA q03xn23
#pragma unroll
    for (int n = 0; n < 2; n++)
#pragma unroll
      for (int kk = 0; kk < 2; kk++)
        b23[n][kk] = *reinterpret_cast<const short8*>(
            sB + (wc * 64 + (2 + n) * 16 + lo) * 64 + ((hi * 8 + kk * 32) ^ swz));
    __builtin_amdgcn_s_barrier();
    FENCE_SCHED();
    __builtin_amdgcn_s_setprio(1);
#pragma unroll
    for (int q = 0; q < 4; q++)
#pragma unroll
      for (int n = 0; n < 2; n++)
#pragma unroll
        for (int kk = 0; kk < 2; kk++)
          acc[q][2 + n] = __builtin_amdgcn_mfma_f32_16x16x32_bf16(af[q][kk], b23[n][kk], acc[q][2 + n], 0, 0, 0);
    __builtin_amdgcn_s_setprio(0);
    __builtin_amdgcn_s_barrier();
    FENCE_SCHED();
    // phase 2: af2 reads; B(t+2)s01; A(t+1)s01 writes; MFMA q47xn23
#pragma unroll
    for (int q = 0; q < 4; q++)
#pragma unroll
      for (int kk = 0; kk < 2; kk++)
        af2[q][kk] = *reinterpret_cast<const short8*>(
            sA + (wr * 128 + (4 + q) * 16 + lo) * 64 + ((hi * 8 + kk * 32) ^ swz));
    if (kt + 2 < NT) { STG_B(kt + 2, 0, cur); STG_B(kt + 2, 1, cur); }
    if (kt + 1 < NT) { WR_A(0, nxt); WR_A(1, nxt); }
    asm volatile("s_waitcnt lgkmcnt(0)" ::: "memory");
    __builtin_amdgcn_s_barrier();
    FENCE_SCHED();
    __builtin_amdgcn_s_setprio(1);
#pragma unroll
    for (int q = 0; q < 4; q++)
#pragma unroll
      for (int n = 0; n < 2; n++)
#pragma unroll
        for (int kk = 0; kk < 2; kk++)
          acc[4 + q][2 + n] = __builtin_amdgcn_mfma_f32_16x16x32_bf16(af2[q][kk], b23[n][kk], acc[4 + q][2 + n], 0, 0, 0);
    __builtin_amdgcn_s_setprio(0);
    __builtin_amdgcn_s_barrier();
    FENCE_SCHED();
    // phase 3: B(t+2)s23; A(t+1)s23 writes; vmcnt(4); MFMA q47xn01
    if (kt + 2 < NT) { STG_B(kt + 2, 2, cur); STG_B(kt + 2, 3, cur); }
    if (kt + 1 < NT) { WR_A(2, nxt); WR_A(3, nxt); }
    asm volatile("s_waitcnt vmcnt(4)" ::: "memory");
    asm volatile("s_waitcnt lgkmcnt(0)" ::: "memory");
    __builtin_amdgcn_s_barrier();
    FENCE_SCHED();
    __builtin_amdgcn_s_setprio(1);
#pragma unroll
    for (int q = 0; q < 4; q++)
#pragma unroll
      for (int n = 0; n < 2; n++)
#pragma unroll
        for (int kk = 0; kk < 2; kk++)
          acc[4 + q][n] = __builtin_amdgcn_mfma_f32_16x16x32_bf16(af2[q][kk], b01[n][kk], acc[4 + q][n], 0, 0, 0);
    __builtin_amdgcn_s_setprio(0);
    __builtin_amdgcn_s_barrier();
    FENCE_SCHED();
  }
#undef LD_A
#undef WR_A
#undef STG_B

  // =================== fused attention epilogue (per wave) ==================
  __syncthreads();                       // all waves done with AS/BS
  // (a) stage Q tile: wave-local [128][64], chunk ^ (row&7) swizzle
  ushort* ep = SMEM + wid * 8192;
#pragma unroll
  for (int mi = 0; mi < 8; mi++)
#pragma unroll
    for (int n = 0; n < 4; n++)
#pragma unroll
      for (int j = 0; j < 4; j++) {
        int row_l = mi * 16 + hi * 4 + j;
        int col = n * 16 + lo;
        ep[row_l * 64 + (((col >> 3) ^ (row_l & 7)) << 3) + (col & 7)] = f2b(acc[mi][n][j]);
      }
  // (b) per-wave head attention, software-pipelined: QK(mi+1) between
  //     P-write(mi) and PV-read(mi); P unnormalized, o scaled by rb post-PV.
  ushort* PS = SMEM + 65536 + wid * 2048;     // 4KB P / out scratch
  int b = m0 >> 12;
  int h = (n0 >> 6) + wc;
  const ushort* Kb = Kall + (size_t)(b * 16 + h) * 96 * 64;
  const ushort* Vb = Vt + (size_t)(b * 16 + h) * 64 * 96;
  short8 kf[6][2], vf[3][4];
#pragma unroll
  for (int ni = 0; ni < 6; ni++)
#pragma unroll
    for (int ks = 0; ks < 2; ks++)
      kf[ni][ks] = *reinterpret_cast<const short8*>(Kb + (ni * 16 + lo) * 64 + ks * 32 + hi * 8);
#pragma unroll
  for (int kk = 0; kk < 3; kk++)
#pragma unroll
    for (int dn = 0; dn < 4; dn++)
      vf[kk][dn] = *reinterpret_cast<const short8*>(Vb + (dn * 16 + lo) * 96 + kk * 32 + hi * 8);
  const float SC = 0.125f * 1.44269504088896340736f;  // 1/sqrt(64) * log2(e)

  short8 qf[2];
  f32x4 s[6];
#define QK_LOAD(mi_) do { \
    _Pragma("unroll") \
    for (int ks = 0; ks < 2; ks++) \
      qf[ks] = *reinterpret_cast<const short8*>( \
          &ep[((mi_) * 16 + lo) * 64 + (((ks * 4 + hi) ^ (lo & 7)) << 3)]); \
  } while (0)
#define QK_MFMA() do { \
    _Pragma("unroll") \
    for (int ni = 0; ni < 6; ni++) { \
      s[ni] = zf; \
      _Pragma("unroll") \
      for (int ks = 0; ks < 2; ks++) \
        s[ni] = __builtin_amdgcn_mfma_f32_16x16x32_bf16(qf[ks], kf[ni][ks], s[ni], 0, 0, 0); \
    } } while (0)

  QK_LOAD(0); QK_MFMA();
  for (int mi = 0; mi < 8; mi++) {
    float rb4[4];
    // softmax -> P (UNNORMALIZED exp; ip entries pre-scaled by sb/si)
#pragma unroll
    for (int j = 0; j < 4; j++) {
      float pb[5];
      float mb = -1e30f;
#pragma unroll
      for (int ni = 0; ni < 5; ni++) {
        int c = ni * 16 + lo;
        float v = s[ni][j] * SC;
        pb[ni] = v;
        if (c < 77) mb = fmaxf(mb, v);
      }
      mb = fmaxf(mb, __shfl_xor(mb, 1, 64));
      mb = fmaxf(mb, __shfl_xor(mb, 2, 64));
      mb = fmaxf(mb, __shfl_xor(mb, 4, 64));
      mb = fmaxf(mb, __shfl_xor(mb, 8, 64));
      float sb = 0.f;
#pragma unroll
      for (int ni = 0; ni < 5; ni++) {
        int c = ni * 16 + lo;
        float p = (c < 77) ? exp2f(pb[ni] - mb) : 0.f;
        pb[ni] = p; sb += p;
      }
      sb += __shfl_xor(sb, 1, 64); sb += __shfl_xor(sb, 2, 64);
      sb += __shfl_xor(sb, 4, 64); sb += __shfl_xor(sb, 8, 64);
      float rb = __builtin_amdgcn_rcpf(sb);
      rb4[j] = rb;
      // ip softmax over lanes lo<4 (cols 80..83); masked-lane write guarded
      float vip = s[5][j] * SC;
      bool val = lo < 4;
      float mip = val ? vip : -1e30f;
      mip = fmaxf(mip, __shfl_xor(mip, 1, 64));
      mip = fmaxf(mip, __shfl_xor(mip, 2, 64));
      float pi = val ? exp2f(vip - mip) : 0.f;
      float si = pi;
      si += __shfl_xor(si, 1, 64); si += __shfl_xor(si, 2, 64);
      ushort* pr = &PS[(hi * 4 + j) * 104];
#pragma unroll
      for (int ni = 0; ni < 5; ni++) pr[ni * 16 + lo] = f2b(pb[ni]);
      pr[80 + lo] = f2b(val ? pi * (sb * __builtin_amdgcn_rcpf(si)) : 0.f);
    }
    // QK for next mi sits between P-write and PV-read (covers DS latency)
    if (mi < 7) { QK_LOAD(mi + 1); QK_MFMA(); }
    // PV (unnormalized P)
    f32x4 o[4];
#pragma unroll
    for (int dn = 0; dn < 4; dn++) o[dn] = zf;
#pragma unroll
    for (int kk = 0; kk < 3; kk++) {
      short8 pf = *reinterpret_cast<const short8*>(&PS[lo * 104 + kk * 32 + hi * 8]);
#pragma unroll
      for (int dn = 0; dn < 4; dn++)
        o[dn] = __builtin_amdgcn_mfma_f32_16x16x32_bf16(pf, vf[kk][dn], o[dn], 0, 0, 0);
    }
    // scale by rb (row = hi*4+j matches lane's rb4[j]); stage; coalesced store
#pragma unroll
    for (int dn = 0; dn < 4; dn++)
#pragma unroll
      for (int j = 0; j < 4; j++)
        PS[(hi * 4 + j) * 64 + dn * 16 + lo] = f2b(o[dn][j] * rb4[j]);
    int gr0 = m0 + wr * 128 + mi * 16;
#pragma unroll
    for (int it = 0; it < 2; it++) {
      int row_o = it * 8 + (l >> 3), c8 = l & 7;
      short8 v = *reinterpret_cast<const short8*>(&PS[row_o * 64 + c8 * 8]);
      *reinterpret_cast<short8*>(&attnO[(size_t)(gr0 + row_o) * 1024 + h * 64 + c8 * 8]) = v;
    }
  }
#undef QK_LOAD
#undef QK_MFMA
}

// ------------------- 6) out GEMM: 8-phase, bf16 A, fp32 C + bias -----------
__global__ __launch_bounds__(512, 2) void k_og8(const ushort* __restrict__ A,
                                                const ushort* __restrict__ Bw,
                                                const float* __restrict__ bias,
                                                float* __restrict__ C) {
  const int K = 1024, NT = 16;
  int wg = blockIdx.x;
  int nid = (wg & 7) * 64 + (wg >> 3);
  int m0 = (nid >> 2) * 256, n0 = (nid & 3) * 256;
  int t = threadIdx.x, wid = t >> 6, l = t & 63, lo = l & 15, hi = l >> 4;
  int wr = wid >> 2, wc = wid & 3;
  __shared__ alignas(16) ushort AS[2][256 * 64];
  __shared__ alignas(16) ushort BS[2][256 * 64];
  f32x4 acc[8][4];
  f32x4 zf = {0.f, 0.f, 0.f, 0.f};
#pragma unroll
  for (int i = 0; i < 8; i++)
#pragma unroll
    for (int j = 0; j < 4; j++) acc[i][j] = zf;
  int tr = t >> 3, tc = t & 7;
  int tcs = tc ^ (tr & 7);
  const ushort* gA = A  + (size_t)(m0 + tr) * K + tcs * 8;
  const ushort* gB = Bw + (size_t)(n0 + tr) * K + tcs * 8;

#define STG_A(kt_, s_, b_) GLD16(gA + (size_t)(s_) * 64 * K + (kt_) * 64, &AS[b_][(s_) * 4096 + wid * 512])
#define STG_B(kt_, s_, b_) GLD16(gB + (size_t)(s_) * 64 * K + (kt_) * 64, &BS[b_][(s_) * 4096 + wid * 512])

  STG_A(0, 0, 0); STG_A(0, 1, 0); STG_A(0, 2, 0); STG_A(0, 3, 0);
  STG_B(0, 0, 0); STG_B(0, 1, 0); STG_B(0, 2, 0); STG_B(0, 3, 0);
  STG_B(1, 0, 1); STG_B(1, 1, 1); STG_B(1, 2, 1); STG_B(1, 3, 1);
  STG_A(1, 0, 1); STG_A(1, 1, 1);
  asm volatile("s_waitcnt vmcnt(6)" ::: "memory");
  __builtin_amdgcn_s_barrier();
  FENCE_SCHED();

  const int swz = (lo & 7) << 3;
  short8 af[4][2], af2[4][2], b01[2][2], b23[2][2];

  for (int kt = 0; kt < NT; kt++) {
    int cur = kt & 1, nxt = cur ^ 1;
    const ushort* sA = &AS[cur][0];
    const ushort* sB = &BS[cur][0];
    // phase 0
#pragma unroll
    for (int q = 0; q < 4; q++)
#pragma unroll
      for (int kk = 0; kk < 2; kk++)
        af[q][kk] = *reinterpret_cast<const short8*>(
            sA + (wr * 128 + q * 16 + lo) * 64 + ((hi * 8 + kk * 32) ^ swz));
#pragma unroll
    for (int n = 0; n < 2; n++)
#pragma unroll
      for (int kk = 0; kk < 2; kk++)
        b01[n][kk] = *reinterpret_cast<const short8*>(
            sB + (wc * 64 + n * 16 + lo) * 64 + ((hi * 8 + kk * 32) ^ swz));
    if (kt + 1 < NT) { STG_A(kt + 1, 2, nxt); STG_A(kt + 1, 3, nxt); }
    __builtin_amdgcn_s_barrier();
    FENCE_SCHED();
    __builtin_amdgcn_s_setprio(1);
#pragma unroll
    for (int q = 0; q < 4; q++)
#pragma unroll
      for (int n = 0; n < 2; n++)
#pragma unroll
        for (int kk = 0; kk < 2; kk++)
          acc[q][n] = __builtin_amdgcn_mfma_f32_16x16x32_bf16(af[q][kk], b01[n][kk], acc[q][n], 0, 0, 0);
    __builtin_amdgcn_s_setprio(0);
    __builtin_amdgcn_s_barrier();
    FENCE_SCHED();
    // phase 1
#pragma unroll
    for (int n = 0; n < 2; n++)
#pragma unroll
      for (int kk = 0; kk < 2; kk++)
        b23[n][kk] = *reinterpret_cast<const short8*>(
            sB + (wc * 64 + (2 + n) * 16 + lo) * 64 + ((hi * 8 + kk * 32) ^ swz));
    __builtin_amdgcn_s_barrier();
    FENCE_SCHED();
    __builtin_amdgcn_s_setprio(1);
#pragma unroll
    for (int q = 0; q < 4; q++)
#pragma unroll
      for (int n = 0; n < 2; n++)
#pragma unroll
        for (int kk = 0; kk < 2; kk++)
          acc[q][2 + n] = __builtin_amdgcn_mfma_f32_16x16x32_bf16(af[q][kk], b23[n][kk], acc[q][2 + n], 0, 0, 0);
    __builtin_amdgcn_s_setprio(0);
    __builtin_amdgcn_s_barrier();
    FENCE_SCHED();
    // phase 2
#pragma unroll
    for (int q = 0; q < 4; q++)
#pragma unroll
      for (int kk = 0; kk < 2; kk++)
        af2[q][kk] = *reinterpret_cast<const short8*>(
            sA + (wr * 128 + (4 + q) * 16 + lo) * 64 + ((hi * 8 + kk * 32) ^ swz));
    if (kt + 2 < NT) { STG_B(kt + 2, 0, cur); STG_B(kt + 2, 1, cur); }
    __builtin_amdgcn_s_barrier();
    FENCE_SCHED();
    __builtin_amdgcn_s_setprio(1);
#pragma unroll
    for (int q = 0; q < 4; q++)
#pragma unroll
      for (int n = 0; n < 2; n++)
#pragma unroll
        for (int kk = 0; kk < 2; kk++)
          acc[4 + q][2 + n] = __builtin_amdgcn_mfma_f32_16x16x32_bf16(af2[q][kk], b23[n][kk], acc[4 + q][2 + n], 0, 0, 0);
    __builtin_amdgcn_s_setprio(0);
    __builtin_amdgcn_s_barrier();
    FENCE_SCHED();
    // phase 3
    if (kt + 2 < NT) {
      STG_B(kt + 2, 2, cur); STG_B(kt + 2, 3, cur);
      STG_A(kt + 2, 0, cur); STG_A(kt + 2, 1, cur);
      asm volatile("s_waitcnt vmcnt(6)" ::: "memory");
    } else {
      asm volatile("s_waitcnt vmcnt(0)" ::: "memory");
    }
    __builtin_amdgcn_s_barrier();
    FENCE_SCHED();
    __builtin_amdgcn_s_setprio(1);
#pragma unroll
    for (int q = 0; q < 4; q++)
#pragma unroll
      for (int n = 0; n < 2; n++)
#pragma unroll
        for (int kk = 0; kk < 2; kk++)
          acc[4 + q][n] = __builtin_amdgcn_mfma_f32_16x16x32_bf16(af2[q][kk], b01[n][kk], acc[4 + q][n], 0, 0, 0);
    __builtin_amdgcn_s_setprio(0);
    __builtin_amdgcn_s_barrier();
    FENCE_SCHED();
  }
#pragma unroll
  for (int n = 0; n < 4; n++) {
    int c = n0 + wc * 64 + n * 16 + lo;
    float bv = bias[c];
#pragma unroll
    for (int mi = 0; mi < 8; mi++)
#pragma unroll
      for (int j = 0; j < 4; j++) {
        int r = m0 + wr * 128 + mi * 16 + hi * 4 + j;
        C[(size_t)r * 1024 + c] = acc[mi][n][j] + bv;
      }
  }
#undef STG_A
#undef STG_B
}

// ---------------------------------------------------------------------------
extern "C" void kernel_launch(void* const* d_in, const int* in_sizes, int n_in,
                              void* d_out, int out_size, void* d_ws, size_t ws_size,
                              hipStream_t stream) {
  const float* hs   = (const float*)d_in[0];
  const float* enc  = (const float*)d_in[1];
  const float* Wq   = (const float*)d_in[2];
  const float* Wk   = (const float*)d_in[3];
  const float* Wv   = (const float*)d_in[4];
  const float* Wkip = (const float*)d_in[5];
  const float* Wvip = (const float*)d_in[6];
  const float* Wo   = (const float*)d_in[7];
  const float* bo   = (const float*)d_in[8];
  const float* lnw  = (const float*)d_in[9];
  const float* lnb  = (const float*)d_in[10];
  float* out = (float*)d_out;

  ushort* p = (ushort*)d_ws;
  ushort* attn    = p; p += (size_t)32768 * 1024;
  ushort* wq_bf   = p; p += (size_t)1024 * 1024;
  ushort* wo_bf   = p; p += (size_t)1024 * 1024;
  ushort* wk_bf   = p; p += (size_t)1024 * 768;
  ushort* wkip_bf = p; p += (size_t)1024 * 768;
  ushort* wv_bf   = p; p += (size_t)1024 * 768;
  ushort* wvip_bf = p; p += (size_t)1024 * 768;
  ushort* xn      = p; p += (size_t)8 * 96 * 768;
  ushort* kall    = p; p += (size_t)8 * 16 * 96 * 64;
  ushort* vtall   = p; p += (size_t)8 * 16 * 96 * 64;

  CvtArgs ca;
  ca.src[0] = Wq;   ca.dst[0] = wq_bf;   ca.n4[0] = 262144;
  ca.src[1] = Wo;   ca.dst[1] = wo_bf;   ca.n4[1] = 262144;
  ca.src[2] = Wk;   ca.dst[2] = wk_bf;   ca.n4[2] = 196608;
  ca.src[3] = Wkip; ca.dst[3] = wkip_bf; ca.n4[3] = 196608;
  ca.src[4] = Wv;   ca.dst[4] = wv_bf;   ca.n4[4] = 196608;
  ca.src[5] = Wvip; ca.dst[5] = wvip_bf; ca.n4[5] = 196608;
  k_prep<<<dim3(1024, 7), 256, 0, stream>>>(ca, enc, lnw, lnb, xn);
  k_kv<<<dim3(4, 8, 2), 256, 0, stream>>>(xn, wk_bf, wkip_bf, wv_bf, wvip_bf, kall, vtall);
  k_qg8<<<512, 512, 0, stream>>>(hs, wq_bf, kall, vtall, attn);
  k_og8<<<512, 512, 0, stream>>>(attn, wo_bf, bo, out);
}

// Round 11
// 291.514 us; speedup vs baseline: 1.5021x; 1.1253x over previous
//
#include <hip/hip_runtime.h>
#include <hip/hip_bf16.h>
#include <stdint.h>

// ---------------------------------------------------------------------------
// CrossViewIPAttnProcessor on MI355X (gfx950)
// B=8, Lq=4096, D=1024, Dc=768, H=16, HD=64, text=77 keys, ip=4 keys
// Round 11:
//  - attn epilogue: no-max softmax (scores bounded, fp32-safe) -> removes the
//    serial 4-shfl max chains (both softmaxes).
//  - qg8: phase-2 lgkmcnt(0) removed (phase-3 drain covers the WR_A hazard).
//  - k_kv: 4x parallelism (grid 16x8x2, 64-col tiles, 1 ni per wave).
// ---------------------------------------------------------------------------

typedef __attribute__((ext_vector_type(8))) short short8;
typedef __attribute__((ext_vector_type(4))) float f32x4;
typedef __attribute__((ext_vector_type(8))) float float8_t;
typedef __attribute__((ext_vector_type(8))) __bf16 bf16x8;
typedef __attribute__((ext_vector_type(4))) __bf16 bf16x4;

__device__ __forceinline__ ushort f2b(float f) {
  __bf16 h = (__bf16)f;
  return __builtin_bit_cast(ushort, h);
}

__device__ __forceinline__ short8 pack2(float4 a, float4 b) {
  float8_t v;
  v[0] = a.x; v[1] = a.y; v[2] = a.z; v[3] = a.w;
  v[4] = b.x; v[5] = b.y; v[6] = b.z; v[7] = b.w;
  return __builtin_bit_cast(short8, __builtin_convertvector(v, bf16x8));
}

#define GLD16(gp, lp) \
  __builtin_amdgcn_global_load_lds((const __attribute__((address_space(1))) uint32_t*)(gp), \
                                   (__attribute__((address_space(3))) uint32_t*)(lp), 16, 0, 0)

#define FENCE_SCHED() __builtin_amdgcn_sched_barrier(0)

// -------- 1+2) fused prep: 6 weight fp32->bf16 segs + Xn builder -----------
struct CvtArgs {
  const float* src[6];
  ushort* dst[6];
  int n4[6];
};

__global__ __launch_bounds__(256) void k_prep(CvtArgs a,
                                              const float* __restrict__ enc,
                                              const float* __restrict__ lnw,
                                              const float* __restrict__ lnb,
                                              ushort* __restrict__ xn) {
  int seg = blockIdx.y;
  if (seg < 6) {
    int i = blockIdx.x * blockDim.x + threadIdx.x;
    if (i >= a.n4[seg]) return;
    float4 v = reinterpret_cast<const float4*>(a.src[seg])[i];
    bf16x4 h;
    h[0] = (__bf16)v.x; h[1] = (__bf16)v.y; h[2] = (__bf16)v.z; h[3] = (__bf16)v.w;
    reinterpret_cast<ushort4*>(a.dst[seg])[i] = __builtin_bit_cast(ushort4, h);
    return;
  }
  // seg == 6: Xn builder (768 blocks used)
  if (blockIdx.x >= 768) return;
  const int Dc = 768;
  int tok = blockIdx.x % 96, b = blockIdx.x / 96, t = threadIdx.x;
  ushort* out = xn + ((size_t)b * 96 + tok) * Dc;
  bool padrow = (tok >= 84) || (tok >= 77 && tok < 80);
  if (padrow) { out[t] = 0; out[t + 256] = 0; out[t + 512] = 0; return; }
  const float* src = (tok < 77) ? enc + ((size_t)b * 81 + tok) * Dc
                                : enc + ((size_t)b * 81 + 77 + (tok - 80)) * Dc;
  float x0 = src[t], x1 = src[t + 256], x2 = src[t + 512];
  if (tok >= 80) { out[t] = f2b(x0); out[t + 256] = f2b(x1); out[t + 512] = f2b(x2); return; }
  float s = x0 + x1 + x2, q = x0 * x0 + x1 * x1 + x2 * x2;
  for (int m = 32; m; m >>= 1) { s += __shfl_xor(s, m, 64); q += __shfl_xor(q, m, 64); }
  __shared__ float rs[4], rq[4];
  int w = t >> 6;
  if ((t & 63) == 0) { rs[w] = s; rq[w] = q; }
  __syncthreads();
  s = rs[0] + rs[1] + rs[2] + rs[3];
  q = rq[0] + rq[1] + rq[2] + rq[3];
  float mean = s * (1.0f / 768.0f);
  float var = q * (1.0f / 768.0f) - mean * mean;
  float rstd = rsqrtf(var + 1e-5f);
  out[t]       = f2b((x0 - mean) * rstd * lnw[t]       + lnb[t]);
  out[t + 256] = f2b((x1 - mean) * rstd * lnw[t + 256] + lnb[t + 256]);
  out[t + 512] = f2b((x2 - mean) * rstd * lnw[t + 512] + lnb[t + 512]);
}

// ------------- 3) K/V projection (grid 16x8x2, 64-col tiles) ---------------
__global__ __launch_bounds__(256) void k_kv(const ushort* __restrict__ xn,
                                            const ushort* __restrict__ wk,
                                            const ushort* __restrict__ wkip,
                                            const ushort* __restrict__ wv,
                                            const ushort* __restrict__ wvip,
                                            ushort* __restrict__ kall,
                                            ushort* __restrict__ vtall) {
  int mode = blockIdx.z;
  const ushort* wb   = mode ? wv   : wk;
  const ushort* wipb = mode ? wvip : wkip;
  ushort* out        = mode ? vtall : kall;
  int n0 = blockIdx.x * 64, b = blockIdx.y;
  int t = threadIdx.x, w = t >> 6, l = t & 63, lo = l & 15, hi = l >> 4;
  __shared__ alignas(16) ushort Xs[96 * 32];
  __shared__ alignas(16) ushort Ws[64 * 32];
  __shared__ alignas(16) ushort Wip[64 * 32];
  f32x4 acc[6];
  f32x4 zf = {0.f, 0.f, 0.f, 0.f};
  for (int i = 0; i < 6; i++) acc[i] = zf;
  const ushort* xb = xn + (size_t)b * 96 * 768;
  for (int k0 = 0; k0 < 768; k0 += 32) {
    __syncthreads();
    for (int i = t; i < 96 * 16; i += 256) {
      int row = i >> 4, p = i & 15;
      reinterpret_cast<uint32_t*>(Xs)[i] =
          *reinterpret_cast<const uint32_t*>(xb + row * 768 + k0 + p * 2);
    }
    for (int i = t; i < 64 * 16; i += 256) {
      int row = i >> 4, p = i & 15;
      reinterpret_cast<uint32_t*>(Ws)[i] =
          *reinterpret_cast<const uint32_t*>(wb + (size_t)(n0 + row) * 768 + k0 + p * 2);
      reinterpret_cast<uint32_t*>(Wip)[i] =
          *reinterpret_cast<const uint32_t*>(wipb + (size_t)(n0 + row) * 768 + k0 + p * 2);
    }
    __syncthreads();
    short8 a[6], bb, bip;
    for (int mi = 0; mi < 6; mi++)
      a[mi] = *reinterpret_cast<const short8*>(Xs + (mi * 16 + lo) * 32 + hi * 8);
    bb  = *reinterpret_cast<const short8*>(Ws  + (w * 16 + lo) * 32 + hi * 8);
    bip = *reinterpret_cast<const short8*>(Wip + (w * 16 + lo) * 32 + hi * 8);
    for (int mi = 0; mi < 5; mi++)
      acc[mi] = __builtin_amdgcn_mfma_f32_16x16x32_bf16(a[mi], bb, acc[mi], 0, 0, 0);
    acc[5] = __builtin_amdgcn_mfma_f32_16x16x32_bf16(a[5], bip, acc[5], 0, 0, 0);
  }
  for (int mi = 0; mi < 6; mi++) {
    int col = n0 + w * 16 + lo;
    int h = col >> 6, dd = col & 63;
    for (int j = 0; j < 4; j++) {
      int tok = mi * 16 + hi * 4 + j;
      ushort v = f2b(acc[mi][j]);
      if (mode == 0) out[(((size_t)b * 16 + h) * 96 + tok) * 64 + dd] = v;
      else           out[(((size_t)b * 16 + h) * 64 + dd) * 96 + tok] = v;
    }
  }
}

// ---------- 4+5) Q GEMM (8-phase, fp32 A reg-staged) + fused attention -----
__global__ __launch_bounds__(512, 2) void k_qg8(const float* __restrict__ A,
                                                const ushort* __restrict__ Bw,
                                                const ushort* __restrict__ Kall,
                                                const ushort* __restrict__ Vt,
                                                ushort* __restrict__ attnO) {
  const int K = 1024, NT = 16;
  int wg = blockIdx.x;
  int nid = (wg & 7) * 64 + (wg >> 3);      // XCD-chunked, nwg=512 (%8==0)
  int m0 = (nid >> 2) * 256, n0 = (nid & 3) * 256;
  int t = threadIdx.x, wid = t >> 6, l = t & 63, lo = l & 15, hi = l >> 4;
  int wr = wid >> 2, wc = wid & 3;
  __shared__ alignas(16) ushort SMEM[81920];        // 160KB
  ushort* ASb = SMEM;                                // A dbuf: 2 x 32KB
  ushort* BSb = SMEM + 32768;                        // B dbuf: 2 x 32KB
  f32x4 acc[8][4];
  f32x4 zf = {0.f, 0.f, 0.f, 0.f};
#pragma unroll
  for (int i = 0; i < 8; i++)
#pragma unroll
    for (int j = 0; j < 4; j++) acc[i][j] = zf;
  int tr = t >> 3, tc = t & 7;
  int tcs = tc ^ (tr & 7);                  // T2 pre-swizzled source chunk
  const float*  gA = A  + (size_t)(m0 + tr) * K + tcs * 8;
  const ushort* gB = Bw + (size_t)(n0 + tr) * K + tcs * 8;
  float4 av[4][2];

#define LD_A(kt_) do { \
    _Pragma("unroll") \
    for (int s_ = 0; s_ < 4; s_++) { \
      av[s_][0] = *reinterpret_cast<const float4*>(gA + (size_t)s_ * 64 * K + (kt_) * 64); \
      av[s_][1] = *reinterpret_cast<const float4*>(gA + (size_t)s_ * 64 * K + (kt_) * 64 + 4); \
    } } while (0)
#define WR_A(s_, b_) \
    *reinterpret_cast<short8*>(&ASb[(b_) * 16384 + (s_) * 4096 + t * 8]) = pack2(av[s_][0], av[s_][1])
#define STG_B(kt_, s_, b_) GLD16(gB + (size_t)(s_) * 64 * K + (kt_) * 64, &BSb[(b_) * 16384 + (s_) * 4096 + wid * 512])

  // ---- prologue ----
  LD_A(0);
  STG_B(0, 0, 0); STG_B(0, 1, 0); STG_B(0, 2, 0); STG_B(0, 3, 0);
  STG_B(1, 0, 1); STG_B(1, 1, 1); STG_B(1, 2, 1); STG_B(1, 3, 1);
  WR_A(0, 0); WR_A(1, 0); WR_A(2, 0); WR_A(3, 0);
  LD_A(1);
  WR_A(0, 1); WR_A(1, 1); WR_A(2, 1); WR_A(3, 1);
  asm volatile("s_waitcnt lgkmcnt(0)" ::: "memory");
  __builtin_amdgcn_s_barrier();
  FENCE_SCHED();

  const int swz = (lo & 7) << 3;
  short8 af[4][2], af2[4][2], b01[2][2], b23[2][2];

  for (int kt = 0; kt < NT; kt++) {
    int cur = kt & 1, nxt = cur ^ 1;
    const ushort* sA = &ASb[cur * 16384];
    const ushort* sB = &BSb[cur * 16384];
    // phase 0: LD_A(t+1); af+b01 reads; MFMA q03xn01
    if (kt + 1 < NT) LD_A(kt + 1);
#pragma unroll
    for (int q = 0; q < 4; q++)
#pragma unroll
      for (int kk = 0; kk < 2; kk++)
        af[q][kk] = *reinterpret_cast<const short8*>(
            sA + (wr * 128 + q * 16 + lo) * 64 + ((hi * 8 + kk * 32) ^ swz));
#pragma unroll
    for (int n = 0; n < 2; n++)
#pragma unroll
      for (int kk = 0; kk < 2; kk++)
        b01[n][kk] = *reinterpret_cast<const short8*>(
            sB + (wc * 64 + n * 16 + lo) * 64 + ((hi * 8 + kk * 32) ^ swz));
    __builtin_amdgcn_s_barrier();
    FENCE_SCHED();
    __builtin_amdgcn_s_setprio(1);
#pragma unroll
    for (int q = 0; q < 4; q++)
#pragma unroll
      for (int n = 0; n < 2; n++)
#pragma unroll
        for (int kk = 0; kk < 2; kk++)
          acc[q][n] = __builtin_amdgcn_mfma_f32_16x16x32_bf16(af[q][kk], b01[n][kk], acc[q][n], 0, 0, 0);
    __builtin_amdgcn_s_setprio(0);
    __builtin_amdgcn_s_barrier();
    FENCE_SCHED();
    // phase 1: b23 reads; MFMA q03xn23
#pragma unroll
    for (int n = 0; n < 2; n++)
#pragma unroll
      for (int kk = 0; kk < 2; kk++)
        b23[n][kk] = *reinterpret_cast<const short8*>(
            sB + (wc * 64 + (2 + n) * 16 + lo) * 64 + ((hi * 8 + kk * 32) ^ swz));
    __builtin_amdgcn_s_barrier();
    FENCE_SCHED();
    __builtin_amdgcn_s_setprio(1);
#pragma unroll
    for (int q = 0; q < 4; q++)
#pragma unroll
      for (int n = 0; n < 2; n++)
#pragma unroll
        for (int kk = 0; kk < 2; kk++)
          acc[q][2 + n] = __builtin_amdgcn_mfma_f32_16x16x32_bf16(af[q][kk], b23[n][kk], acc[q][2 + n], 0, 0, 0);
    __builtin_amdgcn_s_setprio(0);
    __builtin_amdgcn_s_barrier();
    FENCE_SCHED();
    // phase 2: af2 reads; B(t+2)s01; A(t+1)s01 writes; MFMA q47xn23
    //          (no lgkmcnt(0): phase-3 drain covers WR_A; af2 dep is
    //           compiler-tracked)
#pragma unroll
    for (int q = 0; q < 4; q++)
#pragma unroll
      for (int kk = 0; kk < 2; kk++)
        af2[q][kk] = *reinterpret_cast<const short8*>(
            sA + (wr * 128 + (4 + q) * 16 + lo) * 64 + ((hi * 8 + kk * 32) ^ swz));
    if (kt + 2 < NT) { STG_B(kt + 2, 0, cur); STG_B(kt + 2, 1, cur); }
    if (kt + 1 < NT) { WR_A(0, nxt); WR_A(1, nxt); }
    __builtin_amdgcn_s_barrier();
    FENCE_SCHED();
    __builtin_amdgcn_s_setprio(1);
#pragma unroll
    for (int q = 0; q < 4; q++)
#pragma unroll
      for (int n = 0; n < 2; n++)
#pragma unroll
        for (int kk = 0; kk < 2; kk++)
          acc[4 + q][2 + n] = __builtin_amdgcn_mfma_f32_16x16x32_bf16(af2[q][kk], b23[n][kk], acc[4 + q][2 + n], 0, 0, 0);
    __builtin_amdgcn_s_setprio(0);
    __builtin_amdgcn_s_barrier();
    FENCE_SCHED();
    // phase 3: B(t+2)s23; A(t+1)s23 writes; vmcnt(4); lgkmcnt(0); MFMA q47xn01
    if (kt + 2 < NT) { STG_B(kt + 2, 2, cur); STG_B(kt + 2, 3, cur); }
    if (kt + 1 < NT) { WR_A(2, nxt); WR_A(3, nxt); }
    asm volatile("s_waitcnt vmcnt(4)" ::: "memory");
    asm volatile("s_waitcnt lgkmcnt(0)" ::: "memory");
    __builtin_amdgcn_s_barrier();
    FENCE_SCHED();
    __builtin_amdgcn_s_setprio(1);
#pragma unroll
    for (int q = 0; q < 4; q++)
#pragma unroll
      for (int n = 0; n < 2; n++)
#pragma unroll
        for (int kk = 0; kk < 2; kk++)
          acc[4 + q][n] = __builtin_amdgcn_mfma_f32_16x16x32_bf16(af2[q][kk], b01[n][kk], acc[4 + q][n], 0, 0, 0);
    __builtin_amdgcn_s_setprio(0);
    __builtin_amdgcn_s_barrier();
    FENCE_SCHED();
  }
#undef LD_A
#undef WR_A
#undef STG_B

  // =================== fused attention epilogue (per wave) ==================
  __syncthreads();                       // all waves done with AS/BS
  // (a) stage Q tile: wave-local [128][64], chunk ^ (row&7) swizzle
  ushort* ep = SMEM + wid * 8192;
#pragma unroll
  for (int mi = 0; mi < 8; mi++)
#pragma unroll
    for (int n = 0; n < 4; n++)
#pragma unroll
      for (int j = 0; j < 4; j++) {
        int row_l = mi * 16 + hi * 4 + j;
        int col = n * 16 + lo;
        ep[row_l * 64 + (((col >> 3) ^ (row_l & 7)) << 3) + (col & 7)] = f2b(acc[mi][n][j]);
      }
  // (b) per-wave head attention; no-max softmax (bounded scores), P holds
  //     unnormalized exp (ip pre-scaled by sb/si); o scaled by rb post-PV.
  ushort* PS = SMEM + 65536 + wid * 2048;     // 4KB P / out scratch
  int b = m0 >> 12;
  int h = (n0 >> 6) + wc;
  const ushort* Kb = Kall + (size_t)(b * 16 + h) * 96 * 64;
  const ushort* Vb = Vt + (size_t)(b * 16 + h) * 64 * 96;
  short8 kf[6][2], vf[3][4];
#pragma unroll
  for (int ni = 0; ni < 6; ni++)
#pragma unroll
    for (int ks = 0; ks < 2; ks++)
      kf[ni][ks] = *reinterpret_cast<const short8*>(Kb + (ni * 16 + lo) * 64 + ks * 32 + hi * 8);
#pragma unroll
  for (int kk = 0; kk < 3; kk++)
#pragma unroll
    for (int dn = 0; dn < 4; dn++)
      vf[kk][dn] = *reinterpret_cast<const short8*>(Vb + (dn * 16 + lo) * 96 + kk * 32 + hi * 8);
  const float SC = 0.125f * 1.44269504088896340736f;  // 1/sqrt(64) * log2(e)

  short8 qf[2];
  f32x4 s[6];
#define QK_LOAD(mi_) do { \
    _Pragma("unroll") \
    for (int ks = 0; ks < 2; ks++) \
      qf[ks] = *reinterpret_cast<const short8*>( \
          &ep[((mi_) * 16 + lo) * 64 + (((ks * 4 + hi) ^ (lo & 7)) << 3)]); \
  } while (0)
#define QK_MFMA() do { \
    _Pragma("unroll") \
    for (int ni = 0; ni < 6; ni++) { \
      s[ni] = zf; \
      _Pragma("unroll") \
      for (int ks = 0; ks < 2; ks++) \
        s[ni] = __builtin_amdgcn_mfma_f32_16x16x32_bf16(qf[ks], kf[ni][ks], s[ni], 0, 0, 0); \
    } } while (0)

  QK_LOAD(0); QK_MFMA();
  for (int mi = 0; mi < 8; mi++) {
    float rb4[4];
#pragma unroll
    for (int j = 0; j < 4; j++) {
      float pb[5];
      float sb = 0.f;
#pragma unroll
      for (int ni = 0; ni < 5; ni++) {
        int c = ni * 16 + lo;
        float p = (c < 77) ? exp2f(s[ni][j] * SC) : 0.f;
        pb[ni] = p; sb += p;
      }
      sb += __shfl_xor(sb, 1, 64); sb += __shfl_xor(sb, 2, 64);
      sb += __shfl_xor(sb, 4, 64); sb += __shfl_xor(sb, 8, 64);
      rb4[j] = __builtin_amdgcn_rcpf(sb);
      // ip softmax over lanes lo<4 (cols 80..83); masked-lane write guarded
      bool val = lo < 4;
      float pi = val ? exp2f(s[5][j] * SC) : 0.f;
      float si = pi;
      si += __shfl_xor(si, 1, 64); si += __shfl_xor(si, 2, 64);
      ushort* pr = &PS[(hi * 4 + j) * 104];
#pragma unroll
      for (int ni = 0; ni < 5; ni++) pr[ni * 16 + lo] = f2b(pb[ni]);
      pr[80 + lo] = f2b(val ? pi * (sb * __builtin_amdgcn_rcpf(si)) : 0.f);
    }
    // QK for next mi sits between P-write and PV-read (covers DS latency)
    if (mi < 7) { QK_LOAD(mi + 1); QK_MFMA(); }
    // PV (unnormalized P)
    f32x4 o[4];
#pragma unroll
    for (int dn = 0; dn < 4; dn++) o[dn] = zf;
#pragma unroll
    for (int kk = 0; kk < 3; kk++) {
      short8 pf = *reinterpret_cast<const short8*>(&PS[lo * 104 + kk * 32 + hi * 8]);
#pragma unroll
      for (int dn = 0; dn < 4; dn++)
        o[dn] = __builtin_amdgcn_mfma_f32_16x16x32_bf16(pf, vf[kk][dn], o[dn], 0, 0, 0);
    }
    // scale by rb (row = hi*4+j matches lane's rb4[j]); stage; coalesced store
#pragma unroll
    for (int dn = 0; dn < 4; dn++)
#pragma unroll
      for (int j = 0; j < 4; j++)
        PS[(hi * 4 + j) * 64 + dn * 16 + lo] = f2b(o[dn][j] * rb4[j]);
    int gr0 = m0 + wr * 128 + mi * 16;
#pragma unroll
    for (int it = 0; it < 2; it++) {
      int row_o = it * 8 + (l >> 3), c8 = l & 7;
      short8 v = *reinterpret_cast<const short8*>(&PS[row_o * 64 + c8 * 8]);
      *reinterpret_cast<short8*>(&attnO[(size_t)(gr0 + row_o) * 1024 + h * 64 + c8 * 8]) = v;
    }
  }
#undef QK_LOAD
#undef QK_MFMA
}

// ------------------- 6) out GEMM: 8-phase, bf16 A, fp32 C + bias -----------
__global__ __launch_bounds__(512, 2) void k_og8(const ushort* __restrict__ A,
                                                const ushort* __restrict__ Bw,
                                                const float* __restrict__ bias,
                                                float* __restrict__ C) {
  const int K = 1024, NT = 16;
  int wg = blockIdx.x;
  int nid = (wg & 7) * 64 + (wg >> 3);
  int m0 = (nid >> 2) * 256, n0 = (nid & 3) * 256;
  int t = threadIdx.x, wid = t >> 6, l = t & 63, lo = l & 15, hi = l >> 4;
  int wr = wid >> 2, wc = wid & 3;
  __shared__ alignas(16) ushort AS[2][256 * 64];
  __shared__ alignas(16) ushort BS[2][256 * 64];
  f32x4 acc[8][4];
  f32x4 zf = {0.f, 0.f, 0.f, 0.f};
#pragma unroll
  for (int i = 0; i < 8; i++)
#pragma unroll
    for (int j = 0; j < 4; j++) acc[i][j] = zf;
  int tr = t >> 3, tc = t & 7;
  int tcs = tc ^ (tr & 7);
  const ushort* gA = A  + (size_t)(m0 + tr) * K + tcs * 8;
  const ushort* gB = Bw + (size_t)(n0 + tr) * K + tcs * 8;

#define STG_A(kt_, s_, b_) GLD16(gA + (size_t)(s_) * 64 * K + (kt_) * 64, &AS[b_][(s_) * 4096 + wid * 512])
#define STG_B(kt_, s_, b_) GLD16(gB + (size_t)(s_) * 64 * K + (kt_) * 64, &BS[b_][(s_) * 4096 + wid * 512])

  STG_A(0, 0, 0); STG_A(0, 1, 0); STG_A(0, 2, 0); STG_A(0, 3, 0);
  STG_B(0, 0, 0); STG_B(0, 1, 0); STG_B(0, 2, 0); STG_B(0, 3, 0);
  STG_B(1, 0, 1); STG_B(1, 1, 1); STG_B(1, 2, 1); STG_B(1, 3, 1);
  STG_A(1, 0, 1); STG_A(1, 1, 1);
  asm volatile("s_waitcnt vmcnt(6)" ::: "memory");
  __builtin_amdgcn_s_barrier();
  FENCE_SCHED();

  const int swz = (lo & 7) << 3;
  short8 af[4][2], af2[4][2], b01[2][2], b23[2][2];

  for (int kt = 0; kt < NT; kt++) {
    int cur = kt & 1, nxt = cur ^ 1;
    const ushort* sA = &AS[cur][0];
    const ushort* sB = &BS[cur][0];
    // phase 0
#pragma unroll
    for (int q = 0; q < 4; q++)
#pragma unroll
      for (int kk = 0; kk < 2; kk++)
        af[q][kk] = *reinterpret_cast<const short8*>(
            sA + (wr * 128 + q * 16 + lo) * 64 + ((hi * 8 + kk * 32) ^ swz));
#pragma unroll
    for (int n = 0; n < 2; n++)
#pragma unroll
      for (int kk = 0; kk < 2; kk++)
        b01[n][kk] = *reinterpret_cast<const short8*>(
            sB + (wc * 64 + n * 16 + lo) * 64 + ((hi * 8 + kk * 32) ^ swz));
    if (kt + 1 < NT) { STG_A(kt + 1, 2, nxt); STG_A(kt + 1, 3, nxt); }
    __builtin_amdgcn_s_barrier();
    FENCE_SCHED();
    __builtin_amdgcn_s_setprio(1);
#pragma unroll
    for (int q = 0; q < 4; q++)
#pragma unroll
      for (int n = 0; n < 2; n++)
#pragma unroll
        for (int kk = 0; kk < 2; kk++)
          acc[q][n] = __builtin_amdgcn_mfma_f32_16x16x32_bf16(af[q][kk], b01[n][kk], acc[q][n], 0, 0, 0);
    __builtin_amdgcn_s_setprio(0);
    __builtin_amdgcn_s_barrier();
    FENCE_SCHED();
    // phase 1
#pragma unroll
    for (int n = 0; n < 2; n++)
#pragma unroll
      for (int kk = 0; kk < 2; kk++)
        b23[n][kk] = *reinterpret_cast<const short8*>(
            sB + (wc * 64 + (2 + n) * 16 + lo) * 64 + ((hi * 8 + kk * 32) ^ swz));
    __builtin_amdgcn_s_barrier();
    FENCE_SCHED();
    __builtin_amdgcn_s_setprio(1);
#pragma unroll
    for (int q = 0; q < 4; q++)
#pragma unroll
      for (int n = 0; n < 2; n++)
#pragma unroll
        for (int kk = 0; kk < 2; kk++)
          acc[q][2 + n] = __builtin_amdgcn_mfma_f32_16x16x32_bf16(af[q][kk], b23[n][kk], acc[q][2 + n], 0, 0, 0);
    __builtin_amdgcn_s_setprio(0);
    __builtin_amdgcn_s_barrier();
    FENCE_SCHED();
    // phase 2
#pragma unroll
    for (int q = 0; q < 4; q++)
#pragma unroll
      for (int kk = 0; kk < 2; kk++)
        af2[q][kk] = *reinterpret_cast<const short8*>(
            sA + (wr * 128 + (4 + q) * 16 + lo) * 64 + ((hi * 8 + kk * 32) ^ swz));
    if (kt + 2 < NT) { STG_B(kt + 2, 0, cur); STG_B(kt + 2, 1, cur); }
    __builtin_amdgcn_s_barrier();
    FENCE_SCHED();
    __builtin_amdgcn_s_setprio(1);
#pragma unroll
    for (int q = 0; q < 4; q++)
#pragma unroll
      for (int n = 0; n < 2; n++)
#pragma unroll
        for (int kk = 0; kk < 2; kk++)
          acc[4 + q][2 + n] = __builtin_amdgcn_mfma_f32_16x16x32_bf16(af2[q][kk], b23[n][kk], acc[4 + q][2 + n], 0, 0, 0);
    __builtin_amdgcn_s_setprio(0);
    __builtin_amdgcn_s_barrier();
    FENCE_SCHED();
    // phase 3
    if (kt + 2 < NT) {
      STG_B(kt + 2, 2, cur); STG_B(kt + 2, 3, cur);
      STG_A(kt + 2, 0, cur); STG_A(kt + 2, 1, cur);
      asm volatile("s_waitcnt vmcnt(6)" ::: "memory");
    } else {
      asm volatile("s_waitcnt vmcnt(0)" ::: "memory");
    }
    __builtin_amdgcn_s_barrier();
    FENCE_SCHED();
    __builtin_amdgcn_s_setprio(1);
#pragma unroll
    for (int q = 0; q < 4; q++)
#pragma unroll
      for (int n = 0; n < 2; n++)
#pragma unroll
        for (int kk = 0; kk < 2; kk++)
          acc[4 + q][n] = __builtin_amdgcn_mfma_f32_16x16x32_bf16(af2[q][kk], b01[n][kk], acc[4 + q][n], 0, 0, 0);
    __builtin_amdgcn_s_setprio(0);
    __builtin_amdgcn_s_barrier();
    FENCE_SCHED();
  }
#pragma unroll
  for (int n = 0; n < 4; n++) {
    int c = n0 + wc * 64 + n * 16 + lo;
    float bv = bias[c];
#pragma unroll
    for (int mi = 0; mi < 8; mi++)
#pragma unroll
      for (int j = 0; j < 4; j++) {
        int r = m0 + wr * 128 + mi * 16 + hi * 4 + j;
        C[(size_t)r * 1024 + c] = acc[mi][n][j] + bv;
      }
  }
#undef STG_A
#undef STG_B
}

// ---------------------------------------------------------------------------
extern "C" void kernel_launch(void* const* d_in, const int* in_sizes, int n_in,
                              void* d_out, int out_size, void* d_ws, size_t ws_size,
                              hipStream_t stream) {
  const float* hs   = (const float*)d_in[0];
  const float* enc  = (const float*)d_in[1];
  const float* Wq   = (const float*)d_in[2];
  const float* Wk   = (const float*)d_in[3];
  const float* Wv   = (const float*)d_in[4];
  const float* Wkip = (const float*)d_in[5];
  const float* Wvip = (const float*)d_in[6];
  const float* Wo   = (const float*)d_in[7];
  const float* bo   = (const float*)d_in[8];
  const float* lnw  = (const float*)d_in[9];
  const float* lnb  = (const float*)d_in[10];
  float* out = (float*)d_out;

  ushort* p = (ushort*)d_ws;
  ushort* attn    = p; p += (size_t)32768 * 1024;
  ushort* wq_bf   = p; p += (size_t)1024 * 1024;
  ushort* wo_bf   = p; p += (size_t)1024 * 1024;
  ushort* wk_bf   = p; p += (size_t)1024 * 768;
  ushort* wkip_bf = p; p += (size_t)1024 * 768;
  ushort* wv_bf   = p; p += (size_t)1024 * 768;
  ushort* wvip_bf = p; p += (size_t)1024 * 768;
  ushort* xn      = p; p += (size_t)8 * 96 * 768;
  ushort* kall    = p; p += (size_t)8 * 16 * 96 * 64;
  ushort* vtall   = p; p += (size_t)8 * 16 * 96 * 64;

  CvtArgs ca;
  ca.src[0] = Wq;   ca.dst[0] = wq_bf;   ca.n4[0] = 262144;
  ca.src[1] = Wo;   ca.dst[1] = wo_bf;   ca.n4[1] = 262144;
  ca.src[2] = Wk;   ca.dst[2] = wk_bf;   ca.n4[2] = 196608;
  ca.src[3] = Wkip; ca.dst[3] = wkip_bf; ca.n4[3] = 196608;
  ca.src[4] = Wv;   ca.dst[4] = wv_bf;   ca.n4[4] = 196608;
  ca.src[5] = Wvip; ca.dst[5] = wvip_bf; ca.n4[5] = 196608;
  k_prep<<<dim3(1024, 7), 256, 0, stream>>>(ca, enc, lnw, lnb, xn);
  k_kv<<<dim3(16, 8, 2), 256, 0, stream>>>(xn, wk_bf, wkip_bf, wv_bf, wvip_bf, kall, vtall);
  k_qg8<<<512, 512, 0, stream>>>(hs, wq_bf, kall, vtall, attn);
  k_og8<<<512, 512, 0, stream>>>(attn, wo_bf, bo, out);
}

// Round 12
// 287.515 us; speedup vs baseline: 1.5230x; 1.0139x over previous
//
#include <hip/hip_runtime.h>
#include <hip/hip_bf16.h>
#include <stdint.h>

// ---------------------------------------------------------------------------
// CrossViewIPAttnProcessor on MI355X (gfx950)
// B=8, Lq=4096, D=1024, Dc=768, H=16, HD=64, text=77 keys, ip=4 keys
// Round 12:
//  - qg8: LD_A moved p0 -> p3 (3 phases of HBM-latency cover for the av
//    loads before their WR_A consumers; B(t+1) drain proven by in-order
//    retirement at p2's implicit wait).
//  - qg8 epilogue: o-stage LDS layout chunk-XOR swizzled (kills the measured
//    1.44M bank-conflict cycles: 4-way 2B writes -> 2-way(free), read spread).
// ---------------------------------------------------------------------------

typedef __attribute__((ext_vector_type(8))) short short8;
typedef __attribute__((ext_vector_type(4))) float f32x4;
typedef __attribute__((ext_vector_type(8))) float float8_t;
typedef __attribute__((ext_vector_type(8))) __bf16 bf16x8;
typedef __attribute__((ext_vector_type(4))) __bf16 bf16x4;

__device__ __forceinline__ ushort f2b(float f) {
  __bf16 h = (__bf16)f;
  return __builtin_bit_cast(ushort, h);
}

__device__ __forceinline__ short8 pack2(float4 a, float4 b) {
  float8_t v;
  v[0] = a.x; v[1] = a.y; v[2] = a.z; v[3] = a.w;
  v[4] = b.x; v[5] = b.y; v[6] = b.z; v[7] = b.w;
  return __builtin_bit_cast(short8, __builtin_convertvector(v, bf16x8));
}

#define GLD16(gp, lp) \
  __builtin_amdgcn_global_load_lds((const __attribute__((address_space(1))) uint32_t*)(gp), \
                                   (__attribute__((address_space(3))) uint32_t*)(lp), 16, 0, 0)

#define FENCE_SCHED() __builtin_amdgcn_sched_barrier(0)

// -------- 1+2) fused prep: 6 weight fp32->bf16 segs + Xn builder -----------
struct CvtArgs {
  const float* src[6];
  ushort* dst[6];
  int n4[6];
};

__global__ __launch_bounds__(256) void k_prep(CvtArgs a,
                                              const float* __restrict__ enc,
                                              const float* __restrict__ lnw,
                                              const float* __restrict__ lnb,
                                              ushort* __restrict__ xn) {
  int seg = blockIdx.y;
  if (seg < 6) {
    int i = blockIdx.x * blockDim.x + threadIdx.x;
    if (i >= a.n4[seg]) return;
    float4 v = reinterpret_cast<const float4*>(a.src[seg])[i];
    bf16x4 h;
    h[0] = (__bf16)v.x; h[1] = (__bf16)v.y; h[2] = (__bf16)v.z; h[3] = (__bf16)v.w;
    reinterpret_cast<ushort4*>(a.dst[seg])[i] = __builtin_bit_cast(ushort4, h);
    return;
  }
  // seg == 6: Xn builder (768 blocks used)
  if (blockIdx.x >= 768) return;
  const int Dc = 768;
  int tok = blockIdx.x % 96, b = blockIdx.x / 96, t = threadIdx.x;
  ushort* out = xn + ((size_t)b * 96 + tok) * Dc;
  bool padrow = (tok >= 84) || (tok >= 77 && tok < 80);
  if (padrow) { out[t] = 0; out[t + 256] = 0; out[t + 512] = 0; return; }
  const float* src = (tok < 77) ? enc + ((size_t)b * 81 + tok) * Dc
                                : enc + ((size_t)b * 81 + 77 + (tok - 80)) * Dc;
  float x0 = src[t], x1 = src[t + 256], x2 = src[t + 512];
  if (tok >= 80) { out[t] = f2b(x0); out[t + 256] = f2b(x1); out[t + 512] = f2b(x2); return; }
  float s = x0 + x1 + x2, q = x0 * x0 + x1 * x1 + x2 * x2;
  for (int m = 32; m; m >>= 1) { s += __shfl_xor(s, m, 64); q += __shfl_xor(q, m, 64); }
  __shared__ float rs[4], rq[4];
  int w = t >> 6;
  if ((t & 63) == 0) { rs[w] = s; rq[w] = q; }
  __syncthreads();
  s = rs[0] + rs[1] + rs[2] + rs[3];
  q = rq[0] + rq[1] + rq[2] + rq[3];
  float mean = s * (1.0f / 768.0f);
  float var = q * (1.0f / 768.0f) - mean * mean;
  float rstd = rsqrtf(var + 1e-5f);
  out[t]       = f2b((x0 - mean) * rstd * lnw[t]       + lnb[t]);
  out[t + 256] = f2b((x1 - mean) * rstd * lnw[t + 256] + lnb[t + 256]);
  out[t + 512] = f2b((x2 - mean) * rstd * lnw[t + 512] + lnb[t + 512]);
}

// ------------- 3) K/V projection (grid 16x8x2, 64-col tiles) ---------------
__global__ __launch_bounds__(256) void k_kv(const ushort* __restrict__ xn,
                                            const ushort* __restrict__ wk,
                                            const ushort* __restrict__ wkip,
                                            const ushort* __restrict__ wv,
                                            const ushort* __restrict__ wvip,
                                            ushort* __restrict__ kall,
                                            ushort* __restrict__ vtall) {
  int mode = blockIdx.z;
  const ushort* wb   = mode ? wv   : wk;
  const ushort* wipb = mode ? wvip : wkip;
  ushort* out        = mode ? vtall : kall;
  int n0 = blockIdx.x * 64, b = blockIdx.y;
  int t = threadIdx.x, w = t >> 6, l = t & 63, lo = l & 15, hi = l >> 4;
  __shared__ alignas(16) ushort Xs[96 * 32];
  __shared__ alignas(16) ushort Ws[64 * 32];
  __shared__ alignas(16) ushort Wip[64 * 32];
  f32x4 acc[6];
  f32x4 zf = {0.f, 0.f, 0.f, 0.f};
  for (int i = 0; i < 6; i++) acc[i] = zf;
  const ushort* xb = xn + (size_t)b * 96 * 768;
  for (int k0 = 0; k0 < 768; k0 += 32) {
    __syncthreads();
    for (int i = t; i < 96 * 16; i += 256) {
      int row = i >> 4, p = i & 15;
      reinterpret_cast<uint32_t*>(Xs)[i] =
          *reinterpret_cast<const uint32_t*>(xb + row * 768 + k0 + p * 2);
    }
    for (int i = t; i < 64 * 16; i += 256) {
      int row = i >> 4, p = i & 15;
      reinterpret_cast<uint32_t*>(Ws)[i] =
          *reinterpret_cast<const uint32_t*>(wb + (size_t)(n0 + row) * 768 + k0 + p * 2);
      reinterpret_cast<uint32_t*>(Wip)[i] =
          *reinterpret_cast<const uint32_t*>(wipb + (size_t)(n0 + row) * 768 + k0 + p * 2);
    }
    __syncthreads();
    short8 a[6], bb, bip;
    for (int mi = 0; mi < 6; mi++)
      a[mi] = *reinterpret_cast<const short8*>(Xs + (mi * 16 + lo) * 32 + hi * 8);
    bb  = *reinterpret_cast<const short8*>(Ws  + (w * 16 + lo) * 32 + hi * 8);
    bip = *reinterpret_cast<const short8*>(Wip + (w * 16 + lo) * 32 + hi * 8);
    for (int mi = 0; mi < 5; mi++)
      acc[mi] = __builtin_amdgcn_mfma_f32_16x16x32_bf16(a[mi], bb, acc[mi], 0, 0, 0);
    acc[5] = __builtin_amdgcn_mfma_f32_16x16x32_bf16(a[5], bip, acc[5], 0, 0, 0);
  }
  for (int mi = 0; mi < 6; mi++) {
    int col = n0 + w * 16 + lo;
    int h = col >> 6, dd = col & 63;
    for (int j = 0; j < 4; j++) {
      int tok = mi * 16 + hi * 4 + j;
      ushort v = f2b(acc[mi][j]);
      if (mode == 0) out[(((size_t)b * 16 + h) * 96 + tok) * 64 + dd] = v;
      else           out[(((size_t)b * 16 + h) * 64 + dd) * 96 + tok] = v;
    }
  }
}

// ---------- 4+5) Q GEMM (8-phase, fp32 A reg-staged) + fused attention -----
__global__ __launch_bounds__(512, 2) void k_qg8(const float* __restrict__ A,
                                                const ushort* __restrict__ Bw,
                                                const ushort* __restrict__ Kall,
                                                const ushort* __restrict__ Vt,
                                                ushort* __restrict__ attnO) {
  const int K = 1024, NT = 16;
  int wg = blockIdx.x;
  int nid = (wg & 7) * 64 + (wg >> 3);      // XCD-chunked, nwg=512 (%8==0)
  int m0 = (nid >> 2) * 256, n0 = (nid & 3) * 256;
  int t = threadIdx.x, wid = t >> 6, l = t & 63, lo = l & 15, hi = l >> 4;
  int wr = wid >> 2, wc = wid & 3;
  __shared__ alignas(16) ushort SMEM[81920];        // 160KB
  ushort* ASb = SMEM;                                // A dbuf: 2 x 32KB
  ushort* BSb = SMEM + 32768;                        // B dbuf: 2 x 32KB
  f32x4 acc[8][4];
  f32x4 zf = {0.f, 0.f, 0.f, 0.f};
#pragma unroll
  for (int i = 0; i < 8; i++)
#pragma unroll
    for (int j = 0; j < 4; j++) acc[i][j] = zf;
  int tr = t >> 3, tc = t & 7;
  int tcs = tc ^ (tr & 7);                  // T2 pre-swizzled source chunk
  const float*  gA = A  + (size_t)(m0 + tr) * K + tcs * 8;
  const ushort* gB = Bw + (size_t)(n0 + tr) * K + tcs * 8;
  float4 av[4][2];

#define LD_A(kt_) do { \
    _Pragma("unroll") \
    for (int s_ = 0; s_ < 4; s_++) { \
      av[s_][0] = *reinterpret_cast<const float4*>(gA + (size_t)s_ * 64 * K + (kt_) * 64); \
      av[s_][1] = *reinterpret_cast<const float4*>(gA + (size_t)s_ * 64 * K + (kt_) * 64 + 4); \
    } } while (0)
#define WR_A(s_, b_) \
    *reinterpret_cast<short8*>(&ASb[(b_) * 16384 + (s_) * 4096 + t * 8]) = pack2(av[s_][0], av[s_][1])
#define STG_B(kt_, s_, b_) GLD16(gB + (size_t)(s_) * 64 * K + (kt_) * 64, &BSb[(b_) * 16384 + (s_) * 4096 + wid * 512])

  // ---- prologue ----
  LD_A(0);
  STG_B(0, 0, 0); STG_B(0, 1, 0); STG_B(0, 2, 0); STG_B(0, 3, 0);
  STG_B(1, 0, 1); STG_B(1, 1, 1); STG_B(1, 2, 1); STG_B(1, 3, 1);
  WR_A(0, 0); WR_A(1, 0); WR_A(2, 0); WR_A(3, 0);
  LD_A(1);
  WR_A(0, 1); WR_A(1, 1); WR_A(2, 1); WR_A(3, 1);
  asm volatile("s_waitcnt lgkmcnt(0)" ::: "memory");
  __builtin_amdgcn_s_barrier();
  FENCE_SCHED();

  const int swz = (lo & 7) << 3;
  short8 af[4][2], af2[4][2], b01[2][2], b23[2][2];

  for (int kt = 0; kt < NT; kt++) {
    int cur = kt & 1, nxt = cur ^ 1;
    const ushort* sA = &ASb[cur * 16384];
    const ushort* sB = &BSb[cur * 16384];
    // phase 0: af+b01 reads; MFMA q03xn01
#pragma unroll
    for (int q = 0; q < 4; q++)
#pragma unroll
      for (int kk = 0; kk < 2; kk++)
        af[q][kk] = *reinterpret_cast<const short8*>(
            sA + (wr * 128 + q * 16 + lo) * 64 + ((hi * 8 + kk * 32) ^ swz));
#pragma unroll
    for (int n = 0; n < 2; n++)
#pragma unroll
      for (int kk = 0; kk < 2; kk++)
        b01[n][kk] = *reinterpret_cast<const short8*>(
            sB + (wc * 64 + n * 16 + lo) * 64 + ((hi * 8 + kk * 32) ^ swz));
    __builtin_amdgcn_s_barrier();
    FENCE_SCHED();
    __builtin_amdgcn_s_setprio(1);
#pragma unroll
    for (int q = 0; q < 4; q++)
#pragma unroll
      for (int n = 0; n < 2; n++)
#pragma unroll
        for (int kk = 0; kk < 2; kk++)
          acc[q][n] = __builtin_amdgcn_mfma_f32_16x16x32_bf16(af[q][kk], b01[n][kk], acc[q][n], 0, 0, 0);
    __builtin_amdgcn_s_setprio(0);
    __builtin_amdgcn_s_barrier();
    FENCE_SCHED();
    // phase 1: b23 reads; MFMA q03xn23
#pragma unroll
    for (int n = 0; n < 2; n++)
#pragma unroll
      for (int kk = 0; kk < 2; kk++)
        b23[n][kk] = *reinterpret_cast<const short8*>(
            sB + (wc * 64 + (2 + n) * 16 + lo) * 64 + ((hi * 8 + kk * 32) ^ swz));
    __builtin_amdgcn_s_barrier();
    FENCE_SCHED();
    __builtin_amdgcn_s_setprio(1);
#pragma unroll
    for (int q = 0; q < 4; q++)
#pragma unroll
      for (int n = 0; n < 2; n++)
#pragma unroll
        for (int kk = 0; kk < 2; kk++)
          acc[q][2 + n] = __builtin_amdgcn_mfma_f32_16x16x32_bf16(af[q][kk], b23[n][kk], acc[q][2 + n], 0, 0, 0);
    __builtin_amdgcn_s_setprio(0);
    __builtin_amdgcn_s_barrier();
    FENCE_SCHED();
    // phase 2: af2 reads; B(t+2)s01; A(t+1)s01 writes (implicit vmcnt wait
    //          on av, issued p3 of t-1 = 3 phases of cover); MFMA q47xn23
#pragma unroll
    for (int q = 0; q < 4; q++)
#pragma unroll
      for (int kk = 0; kk < 2; kk++)
        af2[q][kk] = *reinterpret_cast<const short8*>(
            sA + (wr * 128 + (4 + q) * 16 + lo) * 64 + ((hi * 8 + kk * 32) ^ swz));
    if (kt + 2 < NT) { STG_B(kt + 2, 0, cur); STG_B(kt + 2, 1, cur); }
    if (kt + 1 < NT) { WR_A(0, nxt); WR_A(1, nxt); }
    __builtin_amdgcn_s_barrier();
    FENCE_SCHED();
    __builtin_amdgcn_s_setprio(1);
#pragma unroll
    for (int q = 0; q < 4; q++)
#pragma unroll
      for (int n = 0; n < 2; n++)
#pragma unroll
        for (int kk = 0; kk < 2; kk++)
          acc[4 + q][2 + n] = __builtin_amdgcn_mfma_f32_16x16x32_bf16(af2[q][kk], b23[n][kk], acc[4 + q][2 + n], 0, 0, 0);
    __builtin_amdgcn_s_setprio(0);
    __builtin_amdgcn_s_barrier();
    FENCE_SCHED();
    // phase 3: B(t+2)s23; A(t+1)s23 writes; vmcnt(4); lgkmcnt(0);
    //          LD_A(t+2) issued AFTER the drains; MFMA q47xn01
    if (kt + 2 < NT) { STG_B(kt + 2, 2, cur); STG_B(kt + 2, 3, cur); }
    if (kt + 1 < NT) { WR_A(2, nxt); WR_A(3, nxt); }
    asm volatile("s_waitcnt vmcnt(4)" ::: "memory");
    asm volatile("s_waitcnt lgkmcnt(0)" ::: "memory");
    if (kt + 2 < NT) LD_A(kt + 2);
    __builtin_amdgcn_s_barrier();
    FENCE_SCHED();
    __builtin_amdgcn_s_setprio(1);
#pragma unroll
    for (int q = 0; q < 4; q++)
#pragma unroll
      for (int n = 0; n < 2; n++)
#pragma unroll
        for (int kk = 0; kk < 2; kk++)
          acc[4 + q][n] = __builtin_amdgcn_mfma_f32_16x16x32_bf16(af2[q][kk], b01[n][kk], acc[4 + q][n], 0, 0, 0);
    __builtin_amdgcn_s_setprio(0);
    __builtin_amdgcn_s_barrier();
    FENCE_SCHED();
  }
#undef LD_A
#undef WR_A
#undef STG_B

  // =================== fused attention epilogue (per wave) ==================
  __syncthreads();                       // all waves done with AS/BS
  // (a) stage Q tile: wave-local [128][64], chunk ^ (row&7) swizzle
  ushort* ep = SMEM + wid * 8192;
#pragma unroll
  for (int mi = 0; mi < 8; mi++)
#pragma unroll
    for (int n = 0; n < 4; n++)
#pragma unroll
      for (int j = 0; j < 4; j++) {
        int row_l = mi * 16 + hi * 4 + j;
        int col = n * 16 + lo;
        ep[row_l * 64 + (((col >> 3) ^ (row_l & 7)) << 3) + (col & 7)] = f2b(acc[mi][n][j]);
      }
  // (b) per-wave head attention; no-max softmax (bounded scores), P holds
  //     unnormalized exp (ip pre-scaled by sb/si); o scaled by rb post-PV.
  ushort* PS = SMEM + 65536 + wid * 2048;     // 4KB P / out scratch
  int b = m0 >> 12;
  int h = (n0 >> 6) + wc;
  const ushort* Kb = Kall + (size_t)(b * 16 + h) * 96 * 64;
  const ushort* Vb = Vt + (size_t)(b * 16 + h) * 64 * 96;
  short8 kf[6][2], vf[3][4];
#pragma unroll
  for (int ni = 0; ni < 6; ni++)
#pragma unroll
    for (int ks = 0; ks < 2; ks++)
      kf[ni][ks] = *reinterpret_cast<const short8*>(Kb + (ni * 16 + lo) * 64 + ks * 32 + hi * 8);
#pragma unroll
  for (int kk = 0; kk < 3; kk++)
#pragma unroll
    for (int dn = 0; dn < 4; dn++)
      vf[kk][dn] = *reinterpret_cast<const short8*>(Vb + (dn * 16 + lo) * 96 + kk * 32 + hi * 8);
  const float SC = 0.125f * 1.44269504088896340736f;  // 1/sqrt(64) * log2(e)

  short8 qf[2];
  f32x4 s[6];
#define QK_LOAD(mi_) do { \
    _Pragma("unroll") \
    for (int ks = 0; ks < 2; ks++) \
      qf[ks] = *reinterpret_cast<const short8*>( \
          &ep[((mi_) * 16 + lo) * 64 + (((ks * 4 + hi) ^ (lo & 7)) << 3)]); \
  } while (0)
#define QK_MFMA() do { \
    _Pragma("unroll") \
    for (int ni = 0; ni < 6; ni++) { \
      s[ni] = zf; \
      _Pragma("unroll") \
      for (int ks = 0; ks < 2; ks++) \
        s[ni] = __builtin_amdgcn_mfma_f32_16x16x32_bf16(qf[ks], kf[ni][ks], s[ni], 0, 0, 0); \
    } } while (0)

  QK_LOAD(0); QK_MFMA();
  for (int mi = 0; mi < 8; mi++) {
    float rb4[4];
#pragma unroll
    for (int j = 0; j < 4; j++) {
      float pb[5];
      float sb = 0.f;
#pragma unroll
      for (int ni = 0; ni < 5; ni++) {
        int c = ni * 16 + lo;
        float p = (c < 77) ? exp2f(s[ni][j] * SC) : 0.f;
        pb[ni] = p; sb += p;
      }
      sb += __shfl_xor(sb, 1, 64); sb += __shfl_xor(sb, 2, 64);
      sb += __shfl_xor(sb, 4, 64); sb += __shfl_xor(sb, 8, 64);
      rb4[j] = __builtin_amdgcn_rcpf(sb);
      // ip softmax over lanes lo<4 (cols 80..83); masked-lane write guarded
      bool val = lo < 4;
      float pi = val ? exp2f(s[5][j] * SC) : 0.f;
      float si = pi;
      si += __shfl_xor(si, 1, 64); si += __shfl_xor(si, 2, 64);
      ushort* pr = &PS[(hi * 4 + j) * 104];
#pragma unroll
      for (int ni = 0; ni < 5; ni++) pr[ni * 16 + lo] = f2b(pb[ni]);
      pr[80 + lo] = f2b(val ? pi * (sb * __builtin_amdgcn_rcpf(si)) : 0.f);
    }
    // QK for next mi sits between P-write and PV-read (covers DS latency)
    if (mi < 7) { QK_LOAD(mi + 1); QK_MFMA(); }
    // PV (unnormalized P)
    f32x4 o[4];
#pragma unroll
    for (int dn = 0; dn < 4; dn++) o[dn] = zf;
#pragma unroll
    for (int kk = 0; kk < 3; kk++) {
      short8 pf = *reinterpret_cast<const short8*>(&PS[lo * 104 + kk * 32 + hi * 8]);
#pragma unroll
      for (int dn = 0; dn < 4; dn++)
        o[dn] = __builtin_amdgcn_mfma_f32_16x16x32_bf16(pf, vf[kk][dn], o[dn], 0, 0, 0);
    }
    // scale by rb; stage via chunk^row swizzle (2B writes 4-way -> 2-way,
    // readback spread); coalesced 16B stores
#pragma unroll
    for (int dn = 0; dn < 4; dn++)
#pragma unroll
      for (int j = 0; j < 4; j++) {
        int row_l = hi * 4 + j;
        int col = dn * 16 + lo;
        PS[row_l * 64 + (((col >> 3) ^ (row_l & 7)) << 3) + (col & 7)] = f2b(o[dn][j] * rb4[j]);
      }
    int gr0 = m0 + wr * 128 + mi * 16;
#pragma unroll
    for (int it = 0; it < 2; it++) {
      int row_o = it * 8 + (l >> 3), c8 = l & 7;
      short8 v = *reinterpret_cast<const short8*>(
          &PS[row_o * 64 + ((c8 ^ (row_o & 7)) << 3)]);
      *reinterpret_cast<short8*>(&attnO[(size_t)(gr0 + row_o) * 1024 + h * 64 + c8 * 8]) = v;
    }
  }
#undef QK_LOAD
#undef QK_MFMA
}

// ------------------- 6) out GEMM: 8-phase, bf16 A, fp32 C + bias -----------
__global__ __launch_bounds__(512, 2) void k_og8(const ushort* __restrict__ A,
                                                const ushort* __restrict__ Bw,
                                                const float* __restrict__ bias,
                                                float* __restrict__ C) {
  const int K = 1024, NT = 16;
  int wg = blockIdx.x;
  int nid = (wg & 7) * 64 + (wg >> 3);
  int m0 = (nid >> 2) * 256, n0 = (nid & 3) * 256;
  int t = threadIdx.x, wid = t >> 6, l = t & 63, lo = l & 15, hi = l >> 4;
  int wr = wid >> 2, wc = wid & 3;
  __shared__ alignas(16) ushort AS[2][256 * 64];
  __shared__ alignas(16) ushort BS[2][256 * 64];
  f32x4 acc[8][4];
  f32x4 zf = {0.f, 0.f, 0.f, 0.f};
#pragma unroll
  for (int i = 0; i < 8; i++)
#pragma unroll
    for (int j = 0; j < 4; j++) acc[i][j] = zf;
  int tr = t >> 3, tc = t & 7;
  int tcs = tc ^ (tr & 7);
  const ushort* gA = A  + (size_t)(m0 + tr) * K + tcs * 8;
  const ushort* gB = Bw + (size_t)(n0 + tr) * K + tcs * 8;

#define STG_A(kt_, s_, b_) GLD16(gA + (size_t)(s_) * 64 * K + (kt_) * 64, &AS[b_][(s_) * 4096 + wid * 512])
#define STG_B(kt_, s_, b_) GLD16(gB + (size_t)(s_) * 64 * K + (kt_) * 64, &BS[b_][(s_) * 4096 + wid * 512])

  STG_A(0, 0, 0); STG_A(0, 1, 0); STG_A(0, 2, 0); STG_A(0, 3, 0);
  STG_B(0, 0, 0); STG_B(0, 1, 0); STG_B(0, 2, 0); STG_B(0, 3, 0);
  STG_B(1, 0, 1); STG_B(1, 1, 1); STG_B(1, 2, 1); STG_B(1, 3, 1);
  STG_A(1, 0, 1); STG_A(1, 1, 1);
  asm volatile("s_waitcnt vmcnt(6)" ::: "memory");
  __builtin_amdgcn_s_barrier();
  FENCE_SCHED();

  const int swz = (lo & 7) << 3;
  short8 af[4][2], af2[4][2], b01[2][2], b23[2][2];

  for (int kt = 0; kt < NT; kt++) {
    int cur = kt & 1, nxt = cur ^ 1;
    const ushort* sA = &AS[cur][0];
    const ushort* sB = &BS[cur][0];
    // phase 0
#pragma unroll
    for (int q = 0; q < 4; q++)
#pragma unroll
      for (int kk = 0; kk < 2; kk++)
        af[q][kk] = *reinterpret_cast<const short8*>(
            sA + (wr * 128 + q * 16 + lo) * 64 + ((hi * 8 + kk * 32) ^ swz));
#pragma unroll
    for (int n = 0; n < 2; n++)
#pragma unroll
      for (int kk = 0; kk < 2; kk++)
        b01[n][kk] = *reinterpret_cast<const short8*>(
            sB + (wc * 64 + n * 16 + lo) * 64 + ((hi * 8 + kk * 32) ^ swz));
    if (kt + 1 < NT) { STG_A(kt + 1, 2, nxt); STG_A(kt + 1, 3, nxt); }
    __builtin_amdgcn_s_barrier();
    FENCE_SCHED();
    __builtin_amdgcn_s_setprio(1);
#pragma unroll
    for (int q = 0; q < 4; q++)
#pragma unroll
      for (int n = 0; n < 2; n++)
#pragma unroll
        for (int kk = 0; kk < 2; kk++)
          acc[q][n] = __builtin_amdgcn_mfma_f32_16x16x32_bf16(af[q][kk], b01[n][kk], acc[q][n], 0, 0, 0);
    __builtin_amdgcn_s_setprio(0);
    __builtin_amdgcn_s_barrier();
    FENCE_SCHED();
    // phase 1
#pragma unroll
    for (int n = 0; n < 2; n++)
#pragma unroll
      for (int kk = 0; kk < 2; kk++)
        b23[n][kk] = *reinterpret_cast<const short8*>(
            sB + (wc * 64 + (2 + n) * 16 + lo) * 64 + ((hi * 8 + kk * 32) ^ swz));
    __builtin_amdgcn_s_barrier();
    FENCE_SCHED();
    __builtin_amdgcn_s_setprio(1);
#pragma unroll
    for (int q = 0; q < 4; q++)
#pragma unroll
      for (int n = 0; n < 2; n++)
#pragma unroll
        for (int kk = 0; kk < 2; kk++)
          acc[q][2 + n] = __builtin_amdgcn_mfma_f32_16x16x32_bf16(af[q][kk], b23[n][kk], acc[q][2 + n], 0, 0, 0);
    __builtin_amdgcn_s_setprio(0);
    __builtin_amdgcn_s_barrier();
    FENCE_SCHED();
    // phase 2
#pragma unroll
    for (int q = 0; q < 4; q++)
#pragma unroll
      for (int kk = 0; kk < 2; kk++)
        af2[q][kk] = *reinterpret_cast<const short8*>(
            sA + (wr * 128 + (4 + q) * 16 + lo) * 64 + ((hi * 8 + kk * 32) ^ swz));
    if (kt + 2 < NT) { STG_B(kt + 2, 0, cur); STG_B(kt + 2, 1, cur); }
    __builtin_amdgcn_s_barrier();
    FENCE_SCHED();
    __builtin_amdgcn_s_setprio(1);
#pragma unroll
    for (int q = 0; q < 4; q++)
#pragma unroll
      for (int n = 0; n < 2; n++)
#pragma unroll
        for (int kk = 0; kk < 2; kk++)
          acc[4 + q][2 + n] = __builtin_amdgcn_mfma_f32_16x16x32_bf16(af2[q][kk], b23[n][kk], acc[4 + q][2 + n], 0, 0, 0);
    __builtin_amdgcn_s_setprio(0);
    __builtin_amdgcn_s_barrier();
    FENCE_SCHED();
    // phase 3
    if (kt + 2 < NT) {
      STG_B(kt + 2, 2, cur); STG_B(kt + 2, 3, cur);
      STG_A(kt + 2, 0, cur); STG_A(kt + 2, 1, cur);
      asm volatile("s_waitcnt vmcnt(6)" ::: "memory");
    } else {
      asm volatile("s_waitcnt vmcnt(0)" ::: "memory");
    }
    __builtin_amdgcn_s_barrier();
    FENCE_SCHED();
    __builtin_amdgcn_s_setprio(1);
#pragma unroll
    for (int q = 0; q < 4; q++)
#pragma unroll
      for (int n = 0; n < 2; n++)
#pragma unroll
        for (int kk = 0; kk < 2; kk++)
          acc[4 + q][n] = __builtin_amdgcn_mfma_f32_16x16x32_bf16(af2[q][kk], b01[n][kk], acc[4 + q][n], 0, 0, 0);
    __builtin_amdgcn_s_setprio(0);
    __builtin_amdgcn_s_barrier();
    FENCE_SCHED();
  }
#pragma unroll
  for (int n = 0; n < 4; n++) {
    int c = n0 + wc * 64 + n * 16 + lo;
    float bv = bias[c];
#pragma unroll
    for (int mi = 0; mi < 8; mi++)
#pragma unroll
      for (int j = 0; j < 4; j++) {
        int r = m0 + wr * 128 + mi * 16 + hi * 4 + j;
        C[(size_t)r * 1024 + c] = acc[mi][n][j] + bv;
      }
  }
#undef STG_A
#undef STG_B
}

// ---------------------------------------------------------------------------
extern "C" void kernel_launch(void* const* d_in, const int* in_sizes, int n_in,
                              void* d_out, int out_size, void* d_ws, size_t ws_size,
                              hipStream_t stream) {
  const float* hs   = (const float*)d_in[0];
  const float* enc  = (const float*)d_in[1];
  const float* Wq   = (const float*)d_in[2];
  const float* Wk   = (const float*)d_in[3];
  const float* Wv   = (const float*)d_in[4];
  const float* Wkip = (const float*)d_in[5];
  const float* Wvip = (const float*)d_in[6];
  const float* Wo   = (const float*)d_in[7];
  const float* bo   = (const float*)d_in[8];
  const float* lnw  = (const float*)d_in[9];
  const float* lnb  = (const float*)d_in[10];
  float* out = (float*)d_out;

  ushort* p = (ushort*)d_ws;
  ushort* attn    = p; p += (size_t)32768 * 1024;
  ushort* wq_bf   = p; p += (size_t)1024 * 1024;
  ushort* wo_bf   = p; p += (size_t)1024 * 1024;
  ushort* wk_bf   = p; p += (size_t)1024 * 768;
  ushort* wkip_bf = p; p += (size_t)1024 * 768;
  ushort* wv_bf   = p; p += (size_t)1024 * 768;
  ushort* wvip_bf = p; p += (size_t)1024 * 768;
  ushort* xn      = p; p += (size_t)8 * 96 * 768;
  ushort* kall    = p; p += (size_t)8 * 16 * 96 * 64;
  ushort* vtall   = p; p += (size_t)8 * 16 * 96 * 64;

  CvtArgs ca;
  ca.src[0] = Wq;   ca.dst[0] = wq_bf;   ca.n4[0] = 262144;
  ca.src[1] = Wo;   ca.dst[1] = wo_bf;   ca.n4[1] = 262144;
  ca.src[2] = Wk;   ca.dst[2] = wk_bf;   ca.n4[2] = 196608;
  ca.src[3] = Wkip; ca.dst[3] = wkip_bf; ca.n4[3] = 196608;
  ca.src[4] = Wv;   ca.dst[4] = wv_bf;   ca.n4[4] = 196608;
  ca.src[5] = Wvip; ca.dst[5] = wvip_bf; ca.n4[5] = 196608;
  k_prep<<<dim3(1024, 7), 256, 0, stream>>>(ca, enc, lnw, lnb, xn);
  k_kv<<<dim3(16, 8, 2), 256, 0, stream>>>(xn, wk_bf, wkip_bf, wv_bf, wvip_bf, kall, vtall);
  k_qg8<<<512, 512, 0, stream>>>(hs, wq_bf, kall, vtall, attn);
  k_og8<<<512, 512, 0, stream>>>(attn, wo_bf, bo, out);
}